// Round 13
// baseline (535.569 us; speedup 1.0000x reference)
//
#include <hip/hip_runtime.h>

#define N_NODES 20000
#define N_EDGES 320000
#define F_DIM   128
#define H_DIM   256
#define M_ROWS  4096
#define NQ      2048
#define NIT     18
#define MM_ROWS 20032   // 313 * 64, padded row count for bf16 [x|msg]

typedef __attribute__((ext_vector_type(8))) short short8;   // 8 bf16 (4 VGPRs)
typedef __attribute__((ext_vector_type(4))) float f32x4;    // MFMA C/D

// ---------------- helpers ----------------

__device__ __forceinline__ float wred(float v) {
#pragma unroll
  for (int m = 32; m > 0; m >>= 1) v += __shfl_xor(v, m, 64);
  return v;
}

__device__ __forceinline__ float bred256(float v, float* lds) {
  v = wred(v);
  int w = threadIdx.x >> 6;
  if ((threadIdx.x & 63) == 0) lds[w] = v;
  __syncthreads();
  float tot = lds[0] + lds[1] + lds[2] + lds[3];
  __syncthreads();
  return tot;
}

// dual reduction: one LDS/barrier round for two independent dots
__device__ __forceinline__ float2 bred256_2(float a, float b, float* lds) {
#pragma unroll
  for (int m = 32; m > 0; m >>= 1) {
    a += __shfl_xor(a, m, 64);
    b += __shfl_xor(b, m, 64);
  }
  int w = threadIdx.x >> 6;
  if ((threadIdx.x & 63) == 0) { lds[w] = a; lds[4 + w] = b; }
  __syncthreads();
  float ta = lds[0] + lds[1] + lds[2] + lds[3];
  float tb = lds[4] + lds[5] + lds[6] + lds[7];
  __syncthreads();
  return make_float2(ta, tb);
}

__device__ __forceinline__ unsigned f2bf(float f) {
  unsigned u = __float_as_uint(f);
  unsigned r = u + 0x7fffu + ((u >> 16) & 1u);
  return r >> 16;
}
__device__ __forceinline__ float bflo(unsigned u) { return __uint_as_float(u << 16); }
__device__ __forceinline__ float bfhi(unsigned u) { return __uint_as_float(u & 0xffff0000u); }

// ---------------- CSR build ----------------

__global__ __launch_bounds__(1024) void k_scan(const int* __restrict__ deg,
    int* __restrict__ rowstart, float* __restrict__ dinv) {
  __shared__ int part[1024];
  int t = threadIdx.x;
  const int chunk = (N_NODES + 1023) / 1024;  // 20
  int lo = t * chunk;
  int hi = lo + chunk; if (hi > N_NODES) hi = N_NODES;
  int s = 0;
  for (int i = lo; i < hi; ++i) {
    int d = deg[i];
    dinv[i] = d > 0 ? rsqrtf((float)d) : 0.f;
    s += d;
  }
  part[t] = s;
  __syncthreads();
  for (int off = 1; off < 1024; off <<= 1) {
    int v = part[t];
    int add = (t >= off) ? part[t - off] : 0;
    __syncthreads();
    part[t] = v + add;
    __syncthreads();
  }
  int base = (t > 0) ? part[t - 1] : 0;
  for (int i = lo; i < hi; ++i) { rowstart[i] = base; base += deg[i]; }
  if (t == 0) rowstart[N_NODES] = part[1023];
}

__global__ __launch_bounds__(256) void k_scatter(const int* __restrict__ ei,
    const int* __restrict__ rowstart, int* __restrict__ cursor,
    const float* __restrict__ dinv, int* __restrict__ cols, float* __restrict__ wvals) {
  int e = blockIdx.x * 256 + threadIdx.x;
  if (e >= N_EDGES) return;
  int r = ei[e];
  int c = ei[N_EDGES + e];
  int pos = rowstart[r] + atomicAdd(&cursor[r], 1);
  cols[pos] = c;
  wvals[pos] = -dinv[r] * dinv[c];
}

// ------- fused front-end: x pack + W pack + degree count ---------------
#define CONVX_BLKS (MM_ROWS * 16 / 256)     // 1252
#define DEG_BLKS   ((N_EDGES + 255) / 256)  // 1250

__global__ __launch_bounds__(256) void k_pack(const float* __restrict__ x,
    const float* __restrict__ W10, const float* __restrict__ W11,
    unsigned* __restrict__ xu, unsigned* __restrict__ Wtb,
    const int* __restrict__ ei, int* __restrict__ deg) {
  int bx = blockIdx.x;
  if (bx < CONVX_BLKS) {
    int gid = bx * 256 + threadIdx.x;
    int row = gid >> 4;
    int q8 = gid & 15;
    uint4* xu4 = (uint4*)xu;
    if (row < N_NODES) {
      const float4* x4 = (const float4*)x;
      float4 a = x4[(size_t)row * 32 + q8 * 2];
      float4 b2 = x4[(size_t)row * 32 + q8 * 2 + 1];
      uint4 u;
      u.x = f2bf(a.x) | (f2bf(a.y) << 16);
      u.y = f2bf(a.z) | (f2bf(a.w) << 16);
      u.z = f2bf(b2.x) | (f2bf(b2.y) << 16);
      u.w = f2bf(b2.z) | (f2bf(b2.w) << 16);
      xu4[(size_t)row * 32 + q8] = u;
    } else {
      uint4 z = make_uint4(0, 0, 0, 0);
      xu4[(size_t)row * 32 + q8] = z;
      xu4[(size_t)row * 32 + 16 + q8] = z;
    }
  } else if (bx < CONVX_BLKS + 128) {
    int gid = (bx - CONVX_BLKS) * 256 + threadIdx.x;  // 0..32767
    int n = gid >> 7;
    int u = gid & 127;
    int k0 = u * 2;
    float v0 = (k0 < 128) ? W10[(size_t)k0 * H_DIM + n]
                          : W11[(size_t)(k0 - 128) * H_DIM + n];
    float v1 = (k0 + 1 < 128) ? W10[(size_t)(k0 + 1) * H_DIM + n]
                              : W11[(size_t)(k0 - 127) * H_DIM + n];
    Wtb[(size_t)n * 128 + u] = f2bf(v0) | (f2bf(v1) << 16);
  } else {
    int e = (bx - CONVX_BLKS - 128) * 256 + threadIdx.x;
    if (e < N_EDGES) atomicAdd(&deg[ei[e]], 1);
  }
}

// ---------------- A^T bf16 prep via LDS transpose (coalesced writes) ----
#define PT_ST 130

__global__ __launch_bounds__(256) void k_prep2(const float* __restrict__ A,
    const float* __restrict__ b, unsigned* __restrict__ Atu,
    float* __restrict__ btA_parts) {
  __shared__ unsigned short T[64 * PT_ST];   // 16640 B
  __shared__ float part[64 * 4];
  const int t = threadIdx.x;
  const int jt = blockIdx.x & 31, kt = blockIdx.x >> 5;
  const int j0 = jt * 64, k0 = kt * 128;
  const int jl = t & 63, kq = t >> 6;        // read: col j0+jl, row k0+p*4+kq
  float bta = 0.f;
#pragma unroll 8
  for (int p = 0; p < 32; ++p) {
    int row = k0 + p * 4 + kq;
    float v = A[(size_t)row * NQ + j0 + jl];
    bta += b[row] * v;
    T[jl * PT_ST + p * 4 + kq] = (unsigned short)f2bf(v);
  }
  part[jl * 4 + kq] = bta;
  __syncthreads();
  // write: 4 threads per Atu row, 16 uints (64B) each -> coalesced 256B/row
  const int jr = t >> 2, c = t & 3;
  const unsigned short* Tr = T + jr * PT_ST + c * 32;
  uint4 uu0, uu1, uu2, uu3;
  uu0.x = (unsigned)Tr[0]  | ((unsigned)Tr[1]  << 16);
  uu0.y = (unsigned)Tr[2]  | ((unsigned)Tr[3]  << 16);
  uu0.z = (unsigned)Tr[4]  | ((unsigned)Tr[5]  << 16);
  uu0.w = (unsigned)Tr[6]  | ((unsigned)Tr[7]  << 16);
  uu1.x = (unsigned)Tr[8]  | ((unsigned)Tr[9]  << 16);
  uu1.y = (unsigned)Tr[10] | ((unsigned)Tr[11] << 16);
  uu1.z = (unsigned)Tr[12] | ((unsigned)Tr[13] << 16);
  uu1.w = (unsigned)Tr[14] | ((unsigned)Tr[15] << 16);
  uu2.x = (unsigned)Tr[16] | ((unsigned)Tr[17] << 16);
  uu2.y = (unsigned)Tr[18] | ((unsigned)Tr[19] << 16);
  uu2.z = (unsigned)Tr[20] | ((unsigned)Tr[21] << 16);
  uu2.w = (unsigned)Tr[22] | ((unsigned)Tr[23] << 16);
  uu3.x = (unsigned)Tr[24] | ((unsigned)Tr[25] << 16);
  uu3.y = (unsigned)Tr[26] | ((unsigned)Tr[27] << 16);
  uu3.z = (unsigned)Tr[28] | ((unsigned)Tr[29] << 16);
  uu3.w = (unsigned)Tr[30] | ((unsigned)Tr[31] << 16);
  uint4* dst = (uint4*)(Atu + (size_t)(j0 + jr) * 2048 + kt * 64 + c * 16);
  dst[0] = uu0; dst[1] = uu1; dst[2] = uu2; dst[3] = uu3;
  if (t < 64) {
    float s4 = (part[t * 4] + part[t * 4 + 1]) + (part[t * 4 + 2] + part[t * 4 + 3]);
    btA_parts[(size_t)kt * NQ + j0 + t] = s4;
  }
}

// ---------------- msg gather, 4-deep unrolled (MLP fix, r10) ------------
__global__ __launch_bounds__(256) void k_msg1(const int* __restrict__ rowstart,
    const int* __restrict__ cols, const float* __restrict__ wvals,
    unsigned* __restrict__ xu) {
  int wid = (blockIdx.x * 256 + threadIdx.x) >> 6;
  int lane = threadIdx.x & 63;
  if (wid >= N_NODES) return;
  int s0 = rowstart[wid], s1 = rowstart[wid + 1];
  float2 a0 = make_float2(0.f, 0.f), a1 = make_float2(0.f, 0.f);
  float2 a2 = make_float2(0.f, 0.f), a3 = make_float2(0.f, 0.f);
  int e = s0;
  for (; e + 4 <= s1; e += 4) {
    int c0 = cols[e], c1 = cols[e + 1], c2 = cols[e + 2], c3 = cols[e + 3];
    float w0 = wvals[e], w1 = wvals[e + 1], w2 = wvals[e + 2], w3 = wvals[e + 3];
    unsigned u0 = xu[(size_t)c0 * 128 + lane];
    unsigned u1 = xu[(size_t)c1 * 128 + lane];
    unsigned u2 = xu[(size_t)c2 * 128 + lane];
    unsigned u3 = xu[(size_t)c3 * 128 + lane];
    a0.x += w0 * bflo(u0); a0.y += w0 * bfhi(u0);
    a1.x += w1 * bflo(u1); a1.y += w1 * bfhi(u1);
    a2.x += w2 * bflo(u2); a2.y += w2 * bfhi(u2);
    a3.x += w3 * bflo(u3); a3.y += w3 * bfhi(u3);
  }
  for (; e < s1; ++e) {
    int c = cols[e];
    float w = wvals[e];
    unsigned u = xu[(size_t)c * 128 + lane];
    a0.x += w * bflo(u); a0.y += w * bfhi(u);
  }
  float ax = (a0.x + a1.x) + (a2.x + a3.x);
  float ay = (a0.y + a1.y) + (a2.y + a3.y);
  xu[(size_t)wid * 128 + 64 + lane] = f2bf(ax) | (f2bf(ay) << 16);
}

// ---------------- GNN layer-1 GEMM via MFMA (LDS-free, barrier-free) ----

__device__ __forceinline__ void mm_ldfrag(short8* Af, short8* Bf,
    const unsigned* __restrict__ xurow, const unsigned* __restrict__ wrow, int kc) {
#pragma unroll
  for (int a = 0; a < 4; ++a)
    Af[a] = *(const short8*)(xurow + (size_t)a * 16 * 128 + kc * 16);
#pragma unroll
  for (int n = 0; n < 4; ++n)
    Bf[n] = *(const short8*)(wrow + (size_t)n * 16 * 128 + kc * 16);
}

__global__ __launch_bounds__(256) void k_mm(const unsigned* __restrict__ xu,
    const unsigned* __restrict__ Wtb, const float* __restrict__ b1,
    const float* __restrict__ W20, const float* __restrict__ W21,
    float* __restrict__ t, float* __restrict__ s) {
  const int row0 = blockIdx.x * 64;
  const int tid = threadIdx.x;
  const int w = tid >> 6, lane = tid & 63;
  const int colb = w * 64;
  const int frow = lane & 15, fqo = (lane >> 4) * 4;
  const int c16 = lane & 15, q4 = lane >> 4;

  f32x4 acc[4][4];
#pragma unroll
  for (int a = 0; a < 4; ++a)
#pragma unroll
    for (int b = 0; b < 4; ++b) {
      acc[a][b][0] = 0.f; acc[a][b][1] = 0.f;
      acc[a][b][2] = 0.f; acc[a][b][3] = 0.f;
    }

  const unsigned* xurow = xu + (size_t)(row0 + frow) * 128 + fqo;
  const unsigned* wrow  = Wtb + (size_t)(colb + frow) * 128 + fqo;

  short8 A0[4], B0[4], A1[4], B1[4];
  mm_ldfrag(A0, B0, xurow, wrow, 0);
#pragma unroll
  for (int kp = 0; kp < 4; ++kp) {
    const int kc = kp * 2;
    mm_ldfrag(A1, B1, xurow, wrow, kc + 1);
#pragma unroll
    for (int a = 0; a < 4; ++a)
#pragma unroll
      for (int n = 0; n < 4; ++n)
        acc[a][n] = __builtin_amdgcn_mfma_f32_16x16x32_bf16(A0[a], B0[n], acc[a][n], 0, 0, 0);
    if (kc + 2 < 8) mm_ldfrag(A0, B0, xurow, wrow, kc + 2);
#pragma unroll
    for (int a = 0; a < 4; ++a)
#pragma unroll
      for (int n = 0; n < 4; ++n)
        acc[a][n] = __builtin_amdgcn_mfma_f32_16x16x32_bf16(A1[a], B1[n], acc[a][n], 0, 0, 0);
  }

  float tp[4][4] = {}, sp[4][4] = {};
#pragma unroll
  for (int b2 = 0; b2 < 4; ++b2) {
    int gc = colb + b2 * 16 + c16;
    float w20 = W20[gc], w21 = W21[gc], bb = b1[gc];
#pragma unroll
    for (int a = 0; a < 4; ++a)
#pragma unroll
      for (int r = 0; r < 4; ++r) {
        float val = acc[a][b2][r] + bb;
        val = val > 0.f ? val : 0.f;
        tp[a][r] += val * w20;
        sp[a][r] += val * w21;
      }
  }
#pragma unroll
  for (int a = 0; a < 4; ++a)
#pragma unroll
    for (int r = 0; r < 4; ++r) {
#pragma unroll
      for (int m = 1; m < 16; m <<= 1) {
        tp[a][r] += __shfl_xor(tp[a][r], m, 64);
        sp[a][r] += __shfl_xor(sp[a][r], m, 64);
      }
    }
  if (c16 == 0) {
#pragma unroll
    for (int a = 0; a < 4; ++a)
#pragma unroll
      for (int r = 0; r < 4; ++r) {
        int gr = row0 + a * 16 + q4 * 4 + r;
        if (gr < N_NODES) {
          atomicAdd(&t[gr], tp[a][r]);
          atomicAdd(&s[gr], sp[a][r]);
        }
      }
  }
}

// ---------------- GNN layer 2 scalar gather (4-deep unrolled) -----------

__global__ __launch_bounds__(256) void k_h2(const float* __restrict__ t,
    const float* __restrict__ s, const int* __restrict__ rowstart,
    const int* __restrict__ cols, const float* __restrict__ wvals,
    const float* __restrict__ lamb, const float* __restrict__ b2, float* __restrict__ h2) {
  int i = blockIdx.x * 256 + threadIdx.x;
  if (i >= N_NODES) return;
  int s0 = rowstart[i], s1 = rowstart[i + 1];
  float m0 = 0.f, m1 = 0.f, m2 = 0.f, m3 = 0.f;
  int e = s0;
  for (; e + 4 <= s1; e += 4) {
    int c0 = cols[e], c1 = cols[e + 1], c2 = cols[e + 2], c3 = cols[e + 3];
    float w0 = wvals[e], w1 = wvals[e + 1], w2 = wvals[e + 2], w3 = wvals[e + 3];
    m0 += w0 * s[c0];
    m1 += w1 * s[c1];
    m2 += w2 * s[c2];
    m3 += w3 * s[c3];
  }
  for (; e < s1; ++e) m0 += wvals[e] * s[cols[e]];
  float m = (m0 + m1) + (m2 + m3);
  float val = t[i] + m + b2[0];
  val = val > 0.f ? val : 0.f;
  h2[i] = lamb[0] * val;
}

// ---------------- G = A^T A upper triangle + FUSED combine --------------
// 544 compute blocks (136 tiles x 4 K-quarters) + 8 qrhs tail blocks.
// Each compute block: MFMA partial -> Gp write -> threadfence ->
// atomicAdd(tilecnt[tile]). The LAST block (old==3) combines the 4
// partials -> bf16 Gb (+mirror via LDS transpose) and writes dex[row] =
// Gsum - bf16(Gsum) for diagonal rows. q is NOT baked into Gb anymore
// (decoupled so the combine has no dependency on the qrhs tail; the CG
// matvec applies (dex+q)*p in fp32 -- algebraically identical).
#define GR_ST2 36
#define NTILE 136
#define GT_ST 131

__global__ __launch_bounds__(512) void k_gram(const unsigned* __restrict__ Atu,
    float* __restrict__ Gp,
    const float* __restrict__ h2, const int* __restrict__ feat_ids,
    const float* __restrict__ x_prior, const float* __restrict__ btA_parts,
    float* __restrict__ q, float* __restrict__ r0,
    unsigned* __restrict__ Gb, float* __restrict__ dex,
    int* __restrict__ tilecnt) {
  if (blockIdx.x >= 544) {
    if (threadIdx.x < 256) {
      int j = (blockIdx.x - 544) * 256 + threadIdx.x;
      int f = feat_ids[j];
      float hf = h2[f] + 1e-5f;
      q[j] = hf;
      float bta = 0.f;
#pragma unroll
      for (int c = 0; c < 32; ++c) bta += btA_parts[(size_t)c * NQ + j];
      r0[j] = x_prior[j] * hf + bta;  // rhs = -p
    }
    return;
  }
  __shared__ unsigned shmem[2 * 128 * GR_ST2];  // 36864 B (also reused as T)
  unsigned* shA = shmem;
  unsigned* shB = shmem + 128 * GR_ST2;
  const int bid = blockIdx.x;            // 0..543
  const int wid = (bid & 7) * 68 + (bid >> 3);
  const int tile = wid >> 2;             // 0..135, tile-major
  const int kq = wid & 3;                // K-quarter: uints [kq*512, kq*512+512)
  int uu = tile, bi = 0;
  while (uu >= 16 - bi) { uu -= 16 - bi; ++bi; }
  const int bj = bi + uu;
  const int i0 = bi * 128, j0 = bj * 128;
  const int tid = threadIdx.x;           // 0..511
  const int w = tid >> 6, lane = tid & 63;
  const int wr = (w >> 2) * 64, wc = (w & 3) * 32;   // 2x4 wave tiles, 64x32 each
  const int srow = tid >> 2, sua = (tid & 3) * 8;    // staging: rows 0..127, 8 uints each
  const int frow = lane & 15, fqo = (lane >> 4) * 4;

  f32x4 acc[4][2];
#pragma unroll
  for (int a = 0; a < 4; ++a)
#pragma unroll
    for (int b = 0; b < 2; ++b) {
      acc[a][b][0] = 0.f; acc[a][b][1] = 0.f;
      acc[a][b][2] = 0.f; acc[a][b][3] = 0.f;
    }

  const unsigned* pa = Atu + (size_t)(i0 + srow) * 2048 + kq * 512 + sua;
  const unsigned* pb = Atu + (size_t)(j0 + srow) * 2048 + kq * 512 + sua;

  uint4 pra0 = *(const uint4*)(pa);
  uint4 pra1 = *(const uint4*)(pa + 4);
  uint4 prb0 = *(const uint4*)(pb);
  uint4 prb1 = *(const uint4*)(pb + 4);

  unsigned* as = shA + srow * GR_ST2 + sua;
  unsigned* bs = shB + srow * GR_ST2 + sua;

  for (int sp = 0; sp < 16; ++sp) {
    *(uint4*)as = pra0; *(uint4*)(as + 4) = pra1;
    *(uint4*)bs = prb0; *(uint4*)(bs + 4) = prb1;
    if (sp + 1 < 16) {
      const int ku = (sp + 1) * 32;
      pra0 = *(const uint4*)(pa + ku);
      pra1 = *(const uint4*)(pa + ku + 4);
      prb0 = *(const uint4*)(pb + ku);
      prb1 = *(const uint4*)(pb + ku + 4);
    }
    __syncthreads();
#pragma unroll
    for (int kk = 0; kk < 2; ++kk) {
      short8 af[4], bf[2];
#pragma unroll
      for (int a = 0; a < 4; ++a)
        af[a] = *(const short8*)(shA + (wr + a * 16 + frow) * GR_ST2 + kk * 16 + fqo);
#pragma unroll
      for (int b2 = 0; b2 < 2; ++b2)
        bf[b2] = *(const short8*)(shB + (wc + b2 * 16 + frow) * GR_ST2 + kk * 16 + fqo);
#pragma unroll
      for (int a = 0; a < 4; ++a)
#pragma unroll
        for (int b2 = 0; b2 < 2; ++b2)
          acc[a][b2] = __builtin_amdgcn_mfma_f32_16x16x32_bf16(af[a], bf[b2], acc[a][b2], 0, 0, 0);
    }
    __syncthreads();
  }

  const int q4 = lane >> 4, c16 = lane & 15;
  float* Gz = Gp + ((size_t)kq * NTILE + tile) * 16384;
#pragma unroll
  for (int a = 0; a < 4; ++a)
#pragma unroll
    for (int b2 = 0; b2 < 2; ++b2)
#pragma unroll
      for (int r = 0; r < 4; ++r) {
        int lr = wr + a * 16 + q4 * 4 + r;
        int lc = wc + b2 * 16 + c16;
        Gz[lr * 128 + lc] = acc[a][b2][r];
      }

  // ---- last-block-per-tile combine (device-scope fence + atomic) ----
  __threadfence();
  __shared__ int lastflag;
  if (tid == 0) lastflag = (atomicAdd(&tilecnt[tile], 1) == 3) ? 1 : 0;
  __syncthreads();
  if (!lastflag) return;
  __threadfence();

  unsigned short* T = (unsigned short*)shmem;   // 33536 B needed <= 36864 B
  const int rr_ = tid >> 2, chh = (tid & 3) * 32;   // row, 32-col slice
  const size_t tbase = (size_t)tile * 16384;
  const float4* P0 = (const float4*)(Gp + tbase + rr_ * 128 + chh);
  const float4* P1 = (const float4*)(Gp + (size_t)1 * NTILE * 16384 + tbase + rr_ * 128 + chh);
  const float4* P2 = (const float4*)(Gp + (size_t)2 * NTILE * 16384 + tbase + rr_ * 128 + chh);
  const float4* P3 = (const float4*)(Gp + (size_t)3 * NTILE * 16384 + tbase + rr_ * 128 + chh);
  const int gr = bi * 128 + rr_;
  const bool hasdiag = (bi == bj) && (rr_ >= chh) && (rr_ < chh + 32);
  unsigned uo[16];
#pragma unroll
  for (int j = 0; j < 8; ++j) {
    float4 a = P0[j], b = P1[j], c = P2[j], d = P3[j];
    float v0 = a.x + b.x + c.x + d.x;
    float v1 = a.y + b.y + c.y + d.y;
    float v2 = a.z + b.z + c.z + d.z;
    float v3 = a.w + b.w + c.w + d.w;
    const int c0 = chh + j * 4;
    if (hasdiag && (rr_ - c0 >= 0) && (rr_ - c0 < 4)) {
      int dsel = rr_ - c0;
      float vd = (dsel == 0) ? v0 : (dsel == 1) ? v1 : (dsel == 2) ? v2 : v3;
      dex[gr] = vd - bflo(f2bf(vd));
    }
    unsigned u0 = f2bf(v0) | (f2bf(v1) << 16);
    unsigned u1 = f2bf(v2) | (f2bf(v3) << 16);
    uo[2 * j] = u0;
    uo[2 * j + 1] = u1;
    T[rr_ * GT_ST + c0]     = (unsigned short)(u0 & 0xffffu);
    T[rr_ * GT_ST + c0 + 1] = (unsigned short)(u0 >> 16);
    T[rr_ * GT_ST + c0 + 2] = (unsigned short)(u1 & 0xffffu);
    T[rr_ * GT_ST + c0 + 3] = (unsigned short)(u1 >> 16);
  }
  uint4* dst = (uint4*)(Gb + (size_t)gr * 1024 + bj * 64 + (chh >> 1));
#pragma unroll
  for (int j = 0; j < 4; ++j) dst[j] = ((const uint4*)uo)[j];
  __syncthreads();
  if (bi != bj) {
    const int wv = tid >> 6, lane_ = tid & 63;
#pragma unroll
    for (int kk = 0; kk < 16; ++kk) {
      int rrr = kk * 8 + wv;
      unsigned lo = T[(2 * lane_) * GT_ST + rrr];
      unsigned hi = T[(2 * lane_ + 1) * GT_ST + rrr];
      Gb[(size_t)(bj * 128 + rrr) * 1024 + bi * 64 + lane_] = lo | (hi << 16);
    }
  }
}

// ---------------- CG: ONE kernel/iter.  Qp = Gb p + (dex+q)*p -----------
// 256 blocks; each wave owns TWO G-rows. Gb rows prefetched at entry so
// their L2 latency hides under the alpha/beta phase.
__global__ __launch_bounds__(256) void k_cgG(int k, const unsigned* __restrict__ Gb,
    const float* __restrict__ dex, const float* __restrict__ q,
    const float* __restrict__ r_old, float* __restrict__ r_new,
    const float* __restrict__ p_old, float* __restrict__ p_new,
    const float* __restrict__ Qp_in, float* __restrict__ Qp_out,
    float* __restrict__ xcg) {
  __shared__ float pshare[NQ];
  __shared__ float lds[8];
  const int tid = threadIdx.x, bid = blockIdx.x;
  const int w = tid >> 6, lane = tid & 63;
  const int row0 = bid * 8 + w * 2;
  const uint4* Gr0 = (const uint4*)(Gb + (size_t)row0 * 1024);
  const uint4* Gr1 = (const uint4*)(Gb + (size_t)(row0 + 1) * 1024);
  uint4 g0a = Gr0[lane],       g1a = Gr1[lane];
  uint4 g0b = Gr0[64 + lane],  g1b = Gr1[64 + lane];
  uint4 g0c = Gr0[128 + lane], g1c = Gr1[128 + lane];
  uint4 g0d = Gr0[192 + lane], g1d = Gr1[192 + lane];

  const float4* r4 = (const float4*)r_old;
  float4 ra = r4[tid * 2], rb2 = r4[tid * 2 + 1];
  float pv[8];
  if (k == 0) {
    pv[0] = ra.x; pv[1] = ra.y; pv[2] = ra.z; pv[3] = ra.w;
    pv[4] = rb2.x; pv[5] = rb2.y; pv[6] = rb2.z; pv[7] = rb2.w;
    if (bid == 0) {
      ((float4*)p_new)[tid * 2] = ra;
      ((float4*)p_new)[tid * 2 + 1] = rb2;
    }
  } else {
    const float4* p4 = (const float4*)p_old;
    const float4* qp4 = (const float4*)Qp_in;
    float4 pa = p4[tid * 2], pb = p4[tid * 2 + 1];
    float4 qa = qp4[tid * 2], qb = qp4[tid * 2 + 1];
    float rr = ra.x * ra.x + ra.y * ra.y + ra.z * ra.z + ra.w * ra.w +
               rb2.x * rb2.x + rb2.y * rb2.y + rb2.z * rb2.z + rb2.w * rb2.w;
    float pap = pa.x * qa.x + pa.y * qa.y + pa.z * qa.z + pa.w * qa.w +
                pb.x * qb.x + pb.y * qb.y + pb.z * qb.z + pb.w * qb.w;
    float2 rp = bred256_2(rr, pap, lds);
    rr = rp.x; pap = rp.y;
    float alpha = rr / pap;
    if (bid == 0) {
      float4* x4 = (float4*)xcg;
      float4 xa = x4[tid * 2], xb = x4[tid * 2 + 1];
      xa.x += alpha * pa.x; xa.y += alpha * pa.y;
      xa.z += alpha * pa.z; xa.w += alpha * pa.w;
      xb.x += alpha * pb.x; xb.y += alpha * pb.y;
      xb.z += alpha * pb.z; xb.w += alpha * pb.w;
      x4[tid * 2] = xa; x4[tid * 2 + 1] = xb;
    }
    ra.x -= alpha * qa.x; ra.y -= alpha * qa.y;
    ra.z -= alpha * qa.z; ra.w -= alpha * qa.w;
    rb2.x -= alpha * qb.x; rb2.y -= alpha * qb.y;
    rb2.z -= alpha * qb.z; rb2.w -= alpha * qb.w;
    float rrn = ra.x * ra.x + ra.y * ra.y + ra.z * ra.z + ra.w * ra.w +
                rb2.x * rb2.x + rb2.y * rb2.y + rb2.z * rb2.z + rb2.w * rb2.w;
    rrn = bred256(rrn, lds);
    float beta = rrn / rr;
    pv[0] = ra.x + beta * pa.x; pv[1] = ra.y + beta * pa.y;
    pv[2] = ra.z + beta * pa.z; pv[3] = ra.w + beta * pa.w;
    pv[4] = rb2.x + beta * pb.x; pv[5] = rb2.y + beta * pb.y;
    pv[6] = rb2.z + beta * pb.z; pv[7] = rb2.w + beta * pb.w;
    if (bid == 0) {
      ((float4*)r_new)[tid * 2] = ra;
      ((float4*)r_new)[tid * 2 + 1] = rb2;
      ((float4*)p_new)[tid * 2] = make_float4(pv[0], pv[1], pv[2], pv[3]);
      ((float4*)p_new)[tid * 2 + 1] = make_float4(pv[4], pv[5], pv[6], pv[7]);
    }
  }
  ((float4*)pshare)[tid * 2] = make_float4(pv[0], pv[1], pv[2], pv[3]);
  ((float4*)pshare)[tid * 2 + 1] = make_float4(pv[4], pv[5], pv[6], pv[7]);
  __syncthreads();
  // matvec: two bf16 G-rows per wave, Gb already in regs
  const float4* ps4 = (const float4*)pshare;
  float acc0 = 0.f, acc1 = 0.f;
#pragma unroll
  for (int c = 0; c < 4; ++c) {
    uint4 g0 = (c == 0) ? g0a : (c == 1) ? g0b : (c == 2) ? g0c : g0d;
    uint4 g1 = (c == 0) ? g1a : (c == 1) ? g1b : (c == 2) ? g1c : g1d;
    float4 pa = ps4[c * 128 + lane * 2];
    float4 pb = ps4[c * 128 + lane * 2 + 1];
    acc0 += bflo(g0.x) * pa.x + bfhi(g0.x) * pa.y;
    acc0 += bflo(g0.y) * pa.z + bfhi(g0.y) * pa.w;
    acc0 += bflo(g0.z) * pb.x + bfhi(g0.z) * pb.y;
    acc0 += bflo(g0.w) * pb.z + bfhi(g0.w) * pb.w;
    acc1 += bflo(g1.x) * pa.x + bfhi(g1.x) * pa.y;
    acc1 += bflo(g1.y) * pa.z + bfhi(g1.y) * pa.w;
    acc1 += bflo(g1.z) * pb.x + bfhi(g1.z) * pb.y;
    acc1 += bflo(g1.w) * pb.z + bfhi(g1.w) * pb.w;
  }
  acc0 = wred(acc0);
  acc1 = wred(acc1);
  if (lane == 0) {
    Qp_out[row0] = acc0 + (dex[row0] + q[row0]) * pshare[row0];
    Qp_out[row0 + 1] = acc1 + (dex[row0 + 1] + q[row0 + 1]) * pshare[row0 + 1];
  }
}

// ---------------- final: alpha + out = x + alpha p -----------------------
__global__ __launch_bounds__(256) void k_cgfin(const float* __restrict__ r_last,
    const float* __restrict__ p_last, const float* __restrict__ Qp,
    const float* __restrict__ xcg, float* __restrict__ out) {
  const int tid = threadIdx.x;
  const int lane = tid & 63;
  const float4* r4 = (const float4*)r_last;
  const float4* p4 = (const float4*)p_last;
  const float4* q4 = (const float4*)Qp;
  float rr = 0.f, pap = 0.f;
#pragma unroll
  for (int c = 0; c < 4; ++c) {
#pragma unroll
    for (int hh = 0; hh < 2; ++hh) {
      float4 rv = r4[c * 128 + lane * 2 + hh];
      float4 pv = p4[c * 128 + lane * 2 + hh];
      float4 qv = q4[c * 128 + lane * 2 + hh];
      rr += rv.x * rv.x + rv.y * rv.y + rv.z * rv.z + rv.w * rv.w;
      pap += pv.x * qv.x + pv.y * qv.y + pv.z * qv.z + pv.w * qv.w;
    }
  }
  rr = wred(rr);
  pap = wred(pap);
  float alpha = rr / pap;
  const float4* x4 = (const float4*)xcg;
  float4* o4 = (float4*)out;
#pragma unroll
  for (int hh = 0; hh < 2; ++hh) {
    int i4 = tid * 2 + hh;
    float4 xv = x4[i4];
    float4 pv = p4[i4];
    xv.x += alpha * pv.x; xv.y += alpha * pv.y;
    xv.z += alpha * pv.z; xv.w += alpha * pv.w;
    o4[i4] = xv;
  }
}

// ---------------- launch ----------------

extern "C" void kernel_launch(void* const* d_in, const int* in_sizes, int n_in,
                              void* d_out, int out_size, void* d_ws, size_t ws_size,
                              hipStream_t stream) {
  const float* x      = (const float*)d_in[0];
  const int*   ei     = (const int*)d_in[1];
  const float* A      = (const float*)d_in[2];
  const float* b      = (const float*)d_in[3];
  const int*   fids   = (const int*)d_in[4];
  const float* xprior = (const float*)d_in[5];
  const float* lamb   = (const float*)d_in[6];
  const float* W10    = (const float*)d_in[7];
  const float* W11    = (const float*)d_in[8];
  const float* b1     = (const float*)d_in[9];
  const float* W20    = (const float*)d_in[10];
  const float* W21    = (const float*)d_in[11];
  const float* b2     = (const float*)d_in[12];
  float* out = (float*)d_out;

  char* base = (char*)d_ws;
  size_t o = 0;
  auto alloc = [&](size_t bytes) { size_t r = o; o = (o + bytes + 255) & ~size_t(255); return r; };

  // zero-init region (deg, cursor, xcg, t, s, tilecnt)
  size_t off_deg    = alloc(N_NODES * 4);
  size_t off_cursor = alloc(N_NODES * 4);
  size_t off_xcg    = alloc(NQ * 4);
  size_t off_t      = alloc(N_NODES * 4);
  size_t off_s      = alloc(N_NODES * 4);
  size_t off_tcnt   = alloc(NTILE * 4);
  size_t zero_end   = o;
  size_t off_rowst  = alloc((N_NODES + 1) * 4);
  size_t off_dinv   = alloc(N_NODES * 4);
  size_t off_h2     = alloc(N_NODES * 4);
  size_t off_q      = alloc(NQ * 4);
  size_t off_r0     = alloc(NQ * 4);
  size_t off_r1     = alloc(NQ * 4);
  size_t off_p0     = alloc(NQ * 4);
  size_t off_p1     = alloc(NQ * 4);
  size_t off_Qp0    = alloc(NQ * 4);
  size_t off_Qp1    = alloc(NQ * 4);
  size_t off_dex    = alloc(NQ * 4);
  size_t off_btAp   = alloc(32 * NQ * 4);
  size_t off_Wtb    = alloc(256 * 128 * 4);
  // union region: GNN {cols, wvals, xmsgb} -> Gb (CG).  Atu SEPARATE.
  size_t sz_cols  = (size_t)N_EDGES * 4 + 256;
  size_t sz_wvals = (size_t)N_EDGES * 4 + 256;
  size_t sz_xmsg  = (size_t)MM_ROWS * 256 * 2;
  size_t union_gnn = sz_cols + sz_wvals + sz_xmsg;
  size_t sz_gb     = (size_t)NQ * NQ * 2;
  size_t off_union = alloc(union_gnn > sz_gb ? union_gnn : sz_gb);
  size_t off_atu   = alloc((size_t)M_ROWS * NQ * 2);          // 16 MB, dedicated
  size_t off_Gp    = alloc((size_t)4 * NTILE * 16384 * 4);    // 35.7 MB
  if (o > ws_size) return;

  int*   deg      = (int*)(base + off_deg);
  int*   cursor   = (int*)(base + off_cursor);
  float* xcg      = (float*)(base + off_xcg);
  float* t        = (float*)(base + off_t);
  float* s        = (float*)(base + off_s);
  int*   tilecnt  = (int*)(base + off_tcnt);
  int*   rowstart = (int*)(base + off_rowst);
  float* dinv     = (float*)(base + off_dinv);
  float* h2       = (float*)(base + off_h2);
  float* q        = (float*)(base + off_q);
  float* rb[2]    = {(float*)(base + off_r0), (float*)(base + off_r1)};
  float* pg[2]    = {(float*)(base + off_p0), (float*)(base + off_p1)};
  float* Qpb[2]   = {(float*)(base + off_Qp0), (float*)(base + off_Qp1)};
  float* dex      = (float*)(base + off_dex);
  float* btA_parts = (float*)(base + off_btAp);
  unsigned* Wtb   = (unsigned*)(base + off_Wtb);
  int*   cols     = (int*)(base + off_union);
  float* wvals    = (float*)(base + off_union + sz_cols);
  unsigned* xmsgb = (unsigned*)(base + off_union + sz_cols + sz_wvals);
  unsigned* Gb    = (unsigned*)(base + off_union);  // overwrites cols/xmsgb AFTER h2/mm
  unsigned* Atu   = (unsigned*)(base + off_atu);
  float* Gp       = (float*)(base + off_Gp);

  hipMemsetAsync(d_ws, 0, zero_end, stream);

  // fused front-end: x/W bf16 pack + edge degree count
  k_pack<<<CONVX_BLKS + 128 + DEG_BLKS, 256, 0, stream>>>(x, W10, W11, xmsgb, Wtb, ei, deg);
  k_scan<<<1, 1024, 0, stream>>>(deg, rowstart, dinv);
  k_scatter<<<DEG_BLKS, 256, 0, stream>>>(ei, rowstart, cursor, dinv, cols, wvals);

  // msg gather (xu still L2-hot from k_pack; no big streams in between)
  k_msg1<<<N_NODES / 4, 256, 0, stream>>>(rowstart, cols, wvals, xmsgb);
  k_mm<<<MM_ROWS / 64, 256, 0, stream>>>(xmsgb, Wtb, b1, W20, W21, t, s);

  // A^T prep (LDS transpose, coalesced) -- after mm so xu stays hot for it
  k_prep2<<<1024, 256, 0, stream>>>(A, b, Atu, btA_parts);

  k_h2<<<(N_NODES + 255) / 256, 256, 0, stream>>>(t, s, rowstart, cols, wvals, lamb, b2, h2);

  // Gram + fused per-tile combine (last block) + qrhs tail (8 blocks)
  k_gram<<<552, 512, 0, stream>>>(Atu, Gp, h2, fids, xprior, btA_parts, q, rb[0],
                                  Gb, dex, tilecnt);

  // CG: 1 kernel/iter
  k_cgG<<<256, 256, 0, stream>>>(0, Gb, dex, q, rb[0], rb[0], pg[0], pg[0],
                                 Qpb[1], Qpb[0], xcg);
  for (int k = 1; k < NIT; ++k) {
    k_cgG<<<256, 256, 0, stream>>>(k, Gb, dex, q, rb[(k - 1) & 1], rb[k & 1],
                                   pg[(k - 1) & 1], pg[k & 1],
                                   Qpb[(k - 1) & 1], Qpb[k & 1], xcg);
  }
  k_cgfin<<<1, 256, 0, stream>>>(rb[(NIT - 1) & 1], pg[(NIT - 1) & 1],
                                 Qpb[(NIT - 1) & 1], xcg, out);
}

// Round 14
// 369.931 us; speedup vs baseline: 1.4478x; 1.4478x over previous
//
#include <hip/hip_runtime.h>

#define N_NODES 20000
#define N_EDGES 320000
#define F_DIM   128
#define H_DIM   256
#define M_ROWS  4096
#define NQ      2048
#define NIT     18
#define MM_ROWS 20032   // 313 * 64, padded row count for bf16 [x|msg]

typedef __attribute__((ext_vector_type(8))) short short8;   // 8 bf16 (4 VGPRs)
typedef __attribute__((ext_vector_type(4))) float f32x4;    // MFMA C/D

// ---------------- helpers ----------------

__device__ __forceinline__ float wred(float v) {
#pragma unroll
  for (int m = 32; m > 0; m >>= 1) v += __shfl_xor(v, m, 64);
  return v;
}

__device__ __forceinline__ float bred256(float v, float* lds) {
  v = wred(v);
  int w = threadIdx.x >> 6;
  if ((threadIdx.x & 63) == 0) lds[w] = v;
  __syncthreads();
  float tot = lds[0] + lds[1] + lds[2] + lds[3];
  __syncthreads();
  return tot;
}

// dual reduction: one LDS/barrier round for two independent dots
__device__ __forceinline__ float2 bred256_2(float a, float b, float* lds) {
#pragma unroll
  for (int m = 32; m > 0; m >>= 1) {
    a += __shfl_xor(a, m, 64);
    b += __shfl_xor(b, m, 64);
  }
  int w = threadIdx.x >> 6;
  if ((threadIdx.x & 63) == 0) { lds[w] = a; lds[4 + w] = b; }
  __syncthreads();
  float ta = lds[0] + lds[1] + lds[2] + lds[3];
  float tb = lds[4] + lds[5] + lds[6] + lds[7];
  __syncthreads();
  return make_float2(ta, tb);
}

__device__ __forceinline__ unsigned f2bf(float f) {
  unsigned u = __float_as_uint(f);
  unsigned r = u + 0x7fffu + ((u >> 16) & 1u);
  return r >> 16;
}
__device__ __forceinline__ float bflo(unsigned u) { return __uint_as_float(u << 16); }
__device__ __forceinline__ float bfhi(unsigned u) { return __uint_as_float(u & 0xffff0000u); }

// ---------------- CSR build ----------------

__global__ __launch_bounds__(1024) void k_scan(const int* __restrict__ deg,
    int* __restrict__ rowstart, float* __restrict__ dinv) {
  __shared__ int part[1024];
  int t = threadIdx.x;
  const int chunk = (N_NODES + 1023) / 1024;  // 20
  int lo = t * chunk;
  int hi = lo + chunk; if (hi > N_NODES) hi = N_NODES;
  int s = 0;
  for (int i = lo; i < hi; ++i) {
    int d = deg[i];
    dinv[i] = d > 0 ? rsqrtf((float)d) : 0.f;
    s += d;
  }
  part[t] = s;
  __syncthreads();
  for (int off = 1; off < 1024; off <<= 1) {
    int v = part[t];
    int add = (t >= off) ? part[t - off] : 0;
    __syncthreads();
    part[t] = v + add;
    __syncthreads();
  }
  int base = (t > 0) ? part[t - 1] : 0;
  for (int i = lo; i < hi; ++i) { rowstart[i] = base; base += deg[i]; }
  if (t == 0) rowstart[N_NODES] = part[1023];
}

__global__ __launch_bounds__(256) void k_scatter(const int* __restrict__ ei,
    const int* __restrict__ rowstart, int* __restrict__ cursor,
    const float* __restrict__ dinv, int* __restrict__ cols, float* __restrict__ wvals) {
  int e = blockIdx.x * 256 + threadIdx.x;
  if (e >= N_EDGES) return;
  int r = ei[e];
  int c = ei[N_EDGES + e];
  int pos = rowstart[r] + atomicAdd(&cursor[r], 1);
  cols[pos] = c;
  wvals[pos] = -dinv[r] * dinv[c];
}

// ------- fused front-end: x pack + W pack + degree count ---------------
#define CONVX_BLKS (MM_ROWS * 16 / 256)     // 1252
#define DEG_BLKS   ((N_EDGES + 255) / 256)  // 1250

__global__ __launch_bounds__(256) void k_pack(const float* __restrict__ x,
    const float* __restrict__ W10, const float* __restrict__ W11,
    unsigned* __restrict__ xu, unsigned* __restrict__ Wtb,
    const int* __restrict__ ei, int* __restrict__ deg) {
  int bx = blockIdx.x;
  if (bx < CONVX_BLKS) {
    int gid = bx * 256 + threadIdx.x;
    int row = gid >> 4;
    int q8 = gid & 15;
    uint4* xu4 = (uint4*)xu;
    if (row < N_NODES) {
      const float4* x4 = (const float4*)x;
      float4 a = x4[(size_t)row * 32 + q8 * 2];
      float4 b2 = x4[(size_t)row * 32 + q8 * 2 + 1];
      uint4 u;
      u.x = f2bf(a.x) | (f2bf(a.y) << 16);
      u.y = f2bf(a.z) | (f2bf(a.w) << 16);
      u.z = f2bf(b2.x) | (f2bf(b2.y) << 16);
      u.w = f2bf(b2.z) | (f2bf(b2.w) << 16);
      xu4[(size_t)row * 32 + q8] = u;
    } else {
      uint4 z = make_uint4(0, 0, 0, 0);
      xu4[(size_t)row * 32 + q8] = z;
      xu4[(size_t)row * 32 + 16 + q8] = z;
    }
  } else if (bx < CONVX_BLKS + 128) {
    int gid = (bx - CONVX_BLKS) * 256 + threadIdx.x;  // 0..32767
    int n = gid >> 7;
    int u = gid & 127;
    int k0 = u * 2;
    float v0 = (k0 < 128) ? W10[(size_t)k0 * H_DIM + n]
                          : W11[(size_t)(k0 - 128) * H_DIM + n];
    float v1 = (k0 + 1 < 128) ? W10[(size_t)(k0 + 1) * H_DIM + n]
                              : W11[(size_t)(k0 - 127) * H_DIM + n];
    Wtb[(size_t)n * 128 + u] = f2bf(v0) | (f2bf(v1) << 16);
  } else {
    int e = (bx - CONVX_BLKS - 128) * 256 + threadIdx.x;
    if (e < N_EDGES) atomicAdd(&deg[ei[e]], 1);
  }
}

// ---------------- A^T bf16 prep via LDS transpose (coalesced writes) ----
#define PT_ST 130

__global__ __launch_bounds__(256) void k_prep2(const float* __restrict__ A,
    const float* __restrict__ b, unsigned* __restrict__ Atu,
    float* __restrict__ btA_parts) {
  __shared__ unsigned short T[64 * PT_ST];   // 16640 B
  __shared__ float part[64 * 4];
  const int t = threadIdx.x;
  const int jt = blockIdx.x & 31, kt = blockIdx.x >> 5;
  const int j0 = jt * 64, k0 = kt * 128;
  const int jl = t & 63, kq = t >> 6;        // read: col j0+jl, row k0+p*4+kq
  float bta = 0.f;
#pragma unroll 8
  for (int p = 0; p < 32; ++p) {
    int row = k0 + p * 4 + kq;
    float v = A[(size_t)row * NQ + j0 + jl];
    bta += b[row] * v;
    T[jl * PT_ST + p * 4 + kq] = (unsigned short)f2bf(v);
  }
  part[jl * 4 + kq] = bta;
  __syncthreads();
  // write: 4 threads per Atu row, 16 uints (64B) each -> coalesced 256B/row
  const int jr = t >> 2, c = t & 3;
  const unsigned short* Tr = T + jr * PT_ST + c * 32;
  uint4 uu0, uu1, uu2, uu3;
  uu0.x = (unsigned)Tr[0]  | ((unsigned)Tr[1]  << 16);
  uu0.y = (unsigned)Tr[2]  | ((unsigned)Tr[3]  << 16);
  uu0.z = (unsigned)Tr[4]  | ((unsigned)Tr[5]  << 16);
  uu0.w = (unsigned)Tr[6]  | ((unsigned)Tr[7]  << 16);
  uu1.x = (unsigned)Tr[8]  | ((unsigned)Tr[9]  << 16);
  uu1.y = (unsigned)Tr[10] | ((unsigned)Tr[11] << 16);
  uu1.z = (unsigned)Tr[12] | ((unsigned)Tr[13] << 16);
  uu1.w = (unsigned)Tr[14] | ((unsigned)Tr[15] << 16);
  uu2.x = (unsigned)Tr[16] | ((unsigned)Tr[17] << 16);
  uu2.y = (unsigned)Tr[18] | ((unsigned)Tr[19] << 16);
  uu2.z = (unsigned)Tr[20] | ((unsigned)Tr[21] << 16);
  uu2.w = (unsigned)Tr[22] | ((unsigned)Tr[23] << 16);
  uu3.x = (unsigned)Tr[24] | ((unsigned)Tr[25] << 16);
  uu3.y = (unsigned)Tr[26] | ((unsigned)Tr[27] << 16);
  uu3.z = (unsigned)Tr[28] | ((unsigned)Tr[29] << 16);
  uu3.w = (unsigned)Tr[30] | ((unsigned)Tr[31] << 16);
  uint4* dst = (uint4*)(Atu + (size_t)(j0 + jr) * 2048 + kt * 64 + c * 16);
  dst[0] = uu0; dst[1] = uu1; dst[2] = uu2; dst[3] = uu3;
  if (t < 64) {
    float s4 = (part[t * 4] + part[t * 4 + 1]) + (part[t * 4 + 2] + part[t * 4 + 3]);
    btA_parts[(size_t)kt * NQ + j0 + t] = s4;
  }
}

// ---------------- msg gather, 4-deep unrolled (MLP fix, r10) ------------
__global__ __launch_bounds__(256) void k_msg1(const int* __restrict__ rowstart,
    const int* __restrict__ cols, const float* __restrict__ wvals,
    unsigned* __restrict__ xu) {
  int wid = (blockIdx.x * 256 + threadIdx.x) >> 6;
  int lane = threadIdx.x & 63;
  if (wid >= N_NODES) return;
  int s0 = rowstart[wid], s1 = rowstart[wid + 1];
  float2 a0 = make_float2(0.f, 0.f), a1 = make_float2(0.f, 0.f);
  float2 a2 = make_float2(0.f, 0.f), a3 = make_float2(0.f, 0.f);
  int e = s0;
  for (; e + 4 <= s1; e += 4) {
    int c0 = cols[e], c1 = cols[e + 1], c2 = cols[e + 2], c3 = cols[e + 3];
    float w0 = wvals[e], w1 = wvals[e + 1], w2 = wvals[e + 2], w3 = wvals[e + 3];
    unsigned u0 = xu[(size_t)c0 * 128 + lane];
    unsigned u1 = xu[(size_t)c1 * 128 + lane];
    unsigned u2 = xu[(size_t)c2 * 128 + lane];
    unsigned u3 = xu[(size_t)c3 * 128 + lane];
    a0.x += w0 * bflo(u0); a0.y += w0 * bfhi(u0);
    a1.x += w1 * bflo(u1); a1.y += w1 * bfhi(u1);
    a2.x += w2 * bflo(u2); a2.y += w2 * bfhi(u2);
    a3.x += w3 * bflo(u3); a3.y += w3 * bfhi(u3);
  }
  for (; e < s1; ++e) {
    int c = cols[e];
    float w = wvals[e];
    unsigned u = xu[(size_t)c * 128 + lane];
    a0.x += w * bflo(u); a0.y += w * bfhi(u);
  }
  float ax = (a0.x + a1.x) + (a2.x + a3.x);
  float ay = (a0.y + a1.y) + (a2.y + a3.y);
  xu[(size_t)wid * 128 + 64 + lane] = f2bf(ax) | (f2bf(ay) << 16);
}

// ---------------- GNN layer-1 GEMM via MFMA (LDS-free, barrier-free) ----

__device__ __forceinline__ void mm_ldfrag(short8* Af, short8* Bf,
    const unsigned* __restrict__ xurow, const unsigned* __restrict__ wrow, int kc) {
#pragma unroll
  for (int a = 0; a < 4; ++a)
    Af[a] = *(const short8*)(xurow + (size_t)a * 16 * 128 + kc * 16);
#pragma unroll
  for (int n = 0; n < 4; ++n)
    Bf[n] = *(const short8*)(wrow + (size_t)n * 16 * 128 + kc * 16);
}

__global__ __launch_bounds__(256) void k_mm(const unsigned* __restrict__ xu,
    const unsigned* __restrict__ Wtb, const float* __restrict__ b1,
    const float* __restrict__ W20, const float* __restrict__ W21,
    float* __restrict__ t, float* __restrict__ s) {
  const int row0 = blockIdx.x * 64;
  const int tid = threadIdx.x;
  const int w = tid >> 6, lane = tid & 63;
  const int colb = w * 64;
  const int frow = lane & 15, fqo = (lane >> 4) * 4;
  const int c16 = lane & 15, q4 = lane >> 4;

  f32x4 acc[4][4];
#pragma unroll
  for (int a = 0; a < 4; ++a)
#pragma unroll
    for (int b = 0; b < 4; ++b) {
      acc[a][b][0] = 0.f; acc[a][b][1] = 0.f;
      acc[a][b][2] = 0.f; acc[a][b][3] = 0.f;
    }

  const unsigned* xurow = xu + (size_t)(row0 + frow) * 128 + fqo;
  const unsigned* wrow  = Wtb + (size_t)(colb + frow) * 128 + fqo;

  short8 A0[4], B0[4], A1[4], B1[4];
  mm_ldfrag(A0, B0, xurow, wrow, 0);
#pragma unroll
  for (int kp = 0; kp < 4; ++kp) {
    const int kc = kp * 2;
    mm_ldfrag(A1, B1, xurow, wrow, kc + 1);
#pragma unroll
    for (int a = 0; a < 4; ++a)
#pragma unroll
      for (int n = 0; n < 4; ++n)
        acc[a][n] = __builtin_amdgcn_mfma_f32_16x16x32_bf16(A0[a], B0[n], acc[a][n], 0, 0, 0);
    if (kc + 2 < 8) mm_ldfrag(A0, B0, xurow, wrow, kc + 2);
#pragma unroll
    for (int a = 0; a < 4; ++a)
#pragma unroll
      for (int n = 0; n < 4; ++n)
        acc[a][n] = __builtin_amdgcn_mfma_f32_16x16x32_bf16(A1[a], B1[n], acc[a][n], 0, 0, 0);
  }

  float tp[4][4] = {}, sp[4][4] = {};
#pragma unroll
  for (int b2 = 0; b2 < 4; ++b2) {
    int gc = colb + b2 * 16 + c16;
    float w20 = W20[gc], w21 = W21[gc], bb = b1[gc];
#pragma unroll
    for (int a = 0; a < 4; ++a)
#pragma unroll
      for (int r = 0; r < 4; ++r) {
        float val = acc[a][b2][r] + bb;
        val = val > 0.f ? val : 0.f;
        tp[a][r] += val * w20;
        sp[a][r] += val * w21;
      }
  }
#pragma unroll
  for (int a = 0; a < 4; ++a)
#pragma unroll
    for (int r = 0; r < 4; ++r) {
#pragma unroll
      for (int m = 1; m < 16; m <<= 1) {
        tp[a][r] += __shfl_xor(tp[a][r], m, 64);
        sp[a][r] += __shfl_xor(sp[a][r], m, 64);
      }
    }
  if (c16 == 0) {
#pragma unroll
    for (int a = 0; a < 4; ++a)
#pragma unroll
      for (int r = 0; r < 4; ++r) {
        int gr = row0 + a * 16 + q4 * 4 + r;
        if (gr < N_NODES) {
          atomicAdd(&t[gr], tp[a][r]);
          atomicAdd(&s[gr], sp[a][r]);
        }
      }
  }
}

// ---------------- GNN layer 2 scalar gather (4-deep unrolled) -----------

__global__ __launch_bounds__(256) void k_h2(const float* __restrict__ t,
    const float* __restrict__ s, const int* __restrict__ rowstart,
    const int* __restrict__ cols, const float* __restrict__ wvals,
    const float* __restrict__ lamb, const float* __restrict__ b2, float* __restrict__ h2) {
  int i = blockIdx.x * 256 + threadIdx.x;
  if (i >= N_NODES) return;
  int s0 = rowstart[i], s1 = rowstart[i + 1];
  float m0 = 0.f, m1 = 0.f, m2 = 0.f, m3 = 0.f;
  int e = s0;
  for (; e + 4 <= s1; e += 4) {
    int c0 = cols[e], c1 = cols[e + 1], c2 = cols[e + 2], c3 = cols[e + 3];
    float w0 = wvals[e], w1 = wvals[e + 1], w2 = wvals[e + 2], w3 = wvals[e + 3];
    m0 += w0 * s[c0];
    m1 += w1 * s[c1];
    m2 += w2 * s[c2];
    m3 += w3 * s[c3];
  }
  for (; e < s1; ++e) m0 += wvals[e] * s[cols[e]];
  float m = (m0 + m1) + (m2 + m3);
  float val = t[i] + m + b2[0];
  val = val > 0.f ? val : 0.f;
  h2[i] = lamb[0] * val;
}

// ---------------- G partials = A^T A, SYMMETRIC upper triangle ----------
// 544 compute blocks (136 tiles x 4 K-quarters, K_STEP=64) + 8 qrhs tail.
// r13 lesson: NO intra-grid cross-XCD combine (threadfence forced Gp
// write-through, 36us -> 235us). Kernel boundary = cheap coherence.
#define GR_ST2 36
#define NTILE 136

__global__ __launch_bounds__(512) void k_gram(const unsigned* __restrict__ Atu,
    float* __restrict__ Gp,
    const float* __restrict__ h2, const int* __restrict__ feat_ids,
    const float* __restrict__ x_prior, const float* __restrict__ btA_parts,
    float* __restrict__ q, float* __restrict__ r0) {
  if (blockIdx.x >= 544) {
    if (threadIdx.x < 256) {
      int j = (blockIdx.x - 544) * 256 + threadIdx.x;
      int f = feat_ids[j];
      float hf = h2[f] + 1e-5f;
      q[j] = hf;
      float bta = 0.f;
#pragma unroll
      for (int c = 0; c < 32; ++c) bta += btA_parts[(size_t)c * NQ + j];
      r0[j] = x_prior[j] * hf + bta;  // rhs = -p
    }
    return;
  }
  __shared__ unsigned shA[128 * GR_ST2];  // 18432 B
  __shared__ unsigned shB[128 * GR_ST2];  // 18432 B
  const int bid = blockIdx.x;            // 0..543
  const int wid = (bid & 7) * 68 + (bid >> 3);
  const int tile = wid >> 2;             // 0..135, tile-major
  const int kq = wid & 3;                // K-quarter: uints [kq*512, kq*512+512)
  int uu = tile, bi = 0;
  while (uu >= 16 - bi) { uu -= 16 - bi; ++bi; }
  const int bj = bi + uu;
  const int i0 = bi * 128, j0 = bj * 128;
  const int tid = threadIdx.x;           // 0..511
  const int w = tid >> 6, lane = tid & 63;
  const int wr = (w >> 2) * 64, wc = (w & 3) * 32;   // 2x4 wave tiles, 64x32 each
  const int srow = tid >> 2, sua = (tid & 3) * 8;    // staging: rows 0..127, 8 uints each
  const int frow = lane & 15, fqo = (lane >> 4) * 4;

  f32x4 acc[4][2];
#pragma unroll
  for (int a = 0; a < 4; ++a)
#pragma unroll
    for (int b = 0; b < 2; ++b) {
      acc[a][b][0] = 0.f; acc[a][b][1] = 0.f;
      acc[a][b][2] = 0.f; acc[a][b][3] = 0.f;
    }

  const unsigned* pa = Atu + (size_t)(i0 + srow) * 2048 + kq * 512 + sua;
  const unsigned* pb = Atu + (size_t)(j0 + srow) * 2048 + kq * 512 + sua;

  uint4 pra0 = *(const uint4*)(pa);
  uint4 pra1 = *(const uint4*)(pa + 4);
  uint4 prb0 = *(const uint4*)(pb);
  uint4 prb1 = *(const uint4*)(pb + 4);

  unsigned* as = shA + srow * GR_ST2 + sua;
  unsigned* bs = shB + srow * GR_ST2 + sua;

  for (int sp = 0; sp < 16; ++sp) {
    *(uint4*)as = pra0; *(uint4*)(as + 4) = pra1;
    *(uint4*)bs = prb0; *(uint4*)(bs + 4) = prb1;
    if (sp + 1 < 16) {
      const int ku = (sp + 1) * 32;
      pra0 = *(const uint4*)(pa + ku);
      pra1 = *(const uint4*)(pa + ku + 4);
      prb0 = *(const uint4*)(pb + ku);
      prb1 = *(const uint4*)(pb + ku + 4);
    }
    __syncthreads();
#pragma unroll
    for (int kk = 0; kk < 2; ++kk) {
      short8 af[4], bf[2];
#pragma unroll
      for (int a = 0; a < 4; ++a)
        af[a] = *(const short8*)(shA + (wr + a * 16 + frow) * GR_ST2 + kk * 16 + fqo);
#pragma unroll
      for (int b2 = 0; b2 < 2; ++b2)
        bf[b2] = *(const short8*)(shB + (wc + b2 * 16 + frow) * GR_ST2 + kk * 16 + fqo);
#pragma unroll
      for (int a = 0; a < 4; ++a)
#pragma unroll
        for (int b2 = 0; b2 < 2; ++b2)
          acc[a][b2] = __builtin_amdgcn_mfma_f32_16x16x32_bf16(af[a], bf[b2], acc[a][b2], 0, 0, 0);
    }
    __syncthreads();
  }

  const int q4 = lane >> 4, c16 = lane & 15;
  float* Gz = Gp + ((size_t)kq * NTILE + tile) * 16384;
#pragma unroll
  for (int a = 0; a < 4; ++a)
#pragma unroll
    for (int b2 = 0; b2 < 2; ++b2)
#pragma unroll
      for (int r = 0; r < 4; ++r) {
        int lr = wr + a * 16 + q4 * 4 + r;
        int lc = wc + b2 * 16 + c16;
        Gz[lr * 128 + lc] = acc[a][b2][r];
      }
}

// ---------------- combine K-quarters + diag(q) -> bf16 Gb (+mirror) -----
#define GT_ST 131

__global__ __launch_bounds__(256) void k_gconv(const float* __restrict__ Gp,
    const float* __restrict__ q, unsigned* __restrict__ Gb, float* __restrict__ qcorr) {
  __shared__ unsigned short T[128 * GT_ST];  // 33536 B
  int uu = blockIdx.x, bi = 0;
  while (uu >= 16 - bi) { uu -= 16 - bi; ++bi; }
  const int bj = bi + uu;
  const int tid = threadIdx.x;
  const int r = tid >> 1, ch = (tid & 1) * 64;   // tile row, col half
  const size_t tile = (size_t)blockIdx.x * 16384;
  const float4* P0 = (const float4*)(Gp + tile + r * 128 + ch);
  const float4* P1 = (const float4*)(Gp + (size_t)1 * NTILE * 16384 + tile + r * 128 + ch);
  const float4* P2 = (const float4*)(Gp + (size_t)2 * NTILE * 16384 + tile + r * 128 + ch);
  const float4* P3 = (const float4*)(Gp + (size_t)3 * NTILE * 16384 + tile + r * 128 + ch);
  const int gr = bi * 128 + r;
  const bool hasdiag = (bi == bj) && (r >= ch) && (r < ch + 64);
  unsigned uo[32];
#pragma unroll
  for (int j = 0; j < 16; ++j) {
    float4 a = P0[j], b = P1[j], c = P2[j], d = P3[j];
    float v0 = a.x + b.x + c.x + d.x;
    float v1 = a.y + b.y + c.y + d.y;
    float v2 = a.z + b.z + c.z + d.z;
    float v3 = a.w + b.w + c.w + d.w;
    const int c0 = ch + j * 4;
    if (hasdiag && (r - c0 >= 0) && (r - c0 < 4)) {
      float qv = q[gr];
      int dsel = r - c0;
      if (dsel == 0) v0 += qv;
      else if (dsel == 1) v1 += qv;
      else if (dsel == 2) v2 += qv;
      else v3 += qv;
      float vd = (dsel == 0) ? v0 : (dsel == 1) ? v1 : (dsel == 2) ? v2 : v3;
      qcorr[gr] = vd - bflo(f2bf(vd));
    }
    unsigned u0 = f2bf(v0) | (f2bf(v1) << 16);
    unsigned u1 = f2bf(v2) | (f2bf(v3) << 16);
    uo[2 * j] = u0;
    uo[2 * j + 1] = u1;
    T[r * GT_ST + c0]     = (unsigned short)(u0 & 0xffffu);
    T[r * GT_ST + c0 + 1] = (unsigned short)(u0 >> 16);
    T[r * GT_ST + c0 + 2] = (unsigned short)(u1 & 0xffffu);
    T[r * GT_ST + c0 + 3] = (unsigned short)(u1 >> 16);
  }
  uint4* dst = (uint4*)(Gb + (size_t)gr * 1024 + bj * 64 + (ch >> 1));
#pragma unroll
  for (int j = 0; j < 8; ++j) dst[j] = ((const uint4*)uo)[j];
  __syncthreads();
  if (bi != bj) {
    const int wv = tid >> 6, lane = tid & 63;
    for (int kk = 0; kk < 32; ++kk) {
      int rr = kk * 4 + wv;
      unsigned lo = T[(2 * lane) * GT_ST + rr];
      unsigned hi = T[(2 * lane + 1) * GT_ST + rr];
      Gb[(size_t)(bj * 128 + rr) * 1024 + bi * 64 + lane] = lo | (hi << 16);
    }
  }
}

// ---------------- CG: ONE kernel/iter.  Qp = Gb p + qcorr*p -------------
// 256 blocks; each wave owns TWO G-rows. Gb rows prefetched at entry so
// their L2 latency hides under the alpha/beta phase; dual reduction saves
// one barrier round per iter.
__global__ __launch_bounds__(256) void k_cgG(int k, const unsigned* __restrict__ Gb,
    const float* __restrict__ qcorr,
    const float* __restrict__ r_old, float* __restrict__ r_new,
    const float* __restrict__ p_old, float* __restrict__ p_new,
    const float* __restrict__ Qp_in, float* __restrict__ Qp_out,
    float* __restrict__ xcg) {
  __shared__ float pshare[NQ];
  __shared__ float lds[8];
  const int tid = threadIdx.x, bid = blockIdx.x;
  const int w = tid >> 6, lane = tid & 63;
  const int row0 = bid * 8 + w * 2;
  const uint4* Gr0 = (const uint4*)(Gb + (size_t)row0 * 1024);
  const uint4* Gr1 = (const uint4*)(Gb + (size_t)(row0 + 1) * 1024);
  uint4 g0a = Gr0[lane],       g1a = Gr1[lane];
  uint4 g0b = Gr0[64 + lane],  g1b = Gr1[64 + lane];
  uint4 g0c = Gr0[128 + lane], g1c = Gr1[128 + lane];
  uint4 g0d = Gr0[192 + lane], g1d = Gr1[192 + lane];

  const float4* r4 = (const float4*)r_old;
  float4 ra = r4[tid * 2], rb2 = r4[tid * 2 + 1];
  float pv[8];
  if (k == 0) {
    pv[0] = ra.x; pv[1] = ra.y; pv[2] = ra.z; pv[3] = ra.w;
    pv[4] = rb2.x; pv[5] = rb2.y; pv[6] = rb2.z; pv[7] = rb2.w;
    if (bid == 0) {
      ((float4*)p_new)[tid * 2] = ra;
      ((float4*)p_new)[tid * 2 + 1] = rb2;
    }
  } else {
    const float4* p4 = (const float4*)p_old;
    const float4* qp4 = (const float4*)Qp_in;
    float4 pa = p4[tid * 2], pb = p4[tid * 2 + 1];
    float4 qa = qp4[tid * 2], qb = qp4[tid * 2 + 1];
    float rr = ra.x * ra.x + ra.y * ra.y + ra.z * ra.z + ra.w * ra.w +
               rb2.x * rb2.x + rb2.y * rb2.y + rb2.z * rb2.z + rb2.w * rb2.w;
    float pap = pa.x * qa.x + pa.y * qa.y + pa.z * qa.z + pa.w * qa.w +
                pb.x * qb.x + pb.y * qb.y + pb.z * qb.z + pb.w * qb.w;
    float2 rp = bred256_2(rr, pap, lds);
    rr = rp.x; pap = rp.y;
    float alpha = rr / pap;
    if (bid == 0) {
      float4* x4 = (float4*)xcg;
      float4 xa = x4[tid * 2], xb = x4[tid * 2 + 1];
      xa.x += alpha * pa.x; xa.y += alpha * pa.y;
      xa.z += alpha * pa.z; xa.w += alpha * pa.w;
      xb.x += alpha * pb.x; xb.y += alpha * pb.y;
      xb.z += alpha * pb.z; xb.w += alpha * pb.w;
      x4[tid * 2] = xa; x4[tid * 2 + 1] = xb;
    }
    ra.x -= alpha * qa.x; ra.y -= alpha * qa.y;
    ra.z -= alpha * qa.z; ra.w -= alpha * qa.w;
    rb2.x -= alpha * qb.x; rb2.y -= alpha * qb.y;
    rb2.z -= alpha * qb.z; rb2.w -= alpha * qb.w;
    float rrn = ra.x * ra.x + ra.y * ra.y + ra.z * ra.z + ra.w * ra.w +
                rb2.x * rb2.x + rb2.y * rb2.y + rb2.z * rb2.z + rb2.w * rb2.w;
    rrn = bred256(rrn, lds);
    float beta = rrn / rr;
    pv[0] = ra.x + beta * pa.x; pv[1] = ra.y + beta * pa.y;
    pv[2] = ra.z + beta * pa.z; pv[3] = ra.w + beta * pa.w;
    pv[4] = rb2.x + beta * pb.x; pv[5] = rb2.y + beta * pb.y;
    pv[6] = rb2.z + beta * pb.z; pv[7] = rb2.w + beta * pb.w;
    if (bid == 0) {
      ((float4*)r_new)[tid * 2] = ra;
      ((float4*)r_new)[tid * 2 + 1] = rb2;
      ((float4*)p_new)[tid * 2] = make_float4(pv[0], pv[1], pv[2], pv[3]);
      ((float4*)p_new)[tid * 2 + 1] = make_float4(pv[4], pv[5], pv[6], pv[7]);
    }
  }
  ((float4*)pshare)[tid * 2] = make_float4(pv[0], pv[1], pv[2], pv[3]);
  ((float4*)pshare)[tid * 2 + 1] = make_float4(pv[4], pv[5], pv[6], pv[7]);
  __syncthreads();
  // matvec: two bf16 G-rows per wave, Gb already in regs
  const float4* ps4 = (const float4*)pshare;
  float acc0 = 0.f, acc1 = 0.f;
#pragma unroll
  for (int c = 0; c < 4; ++c) {
    uint4 g0 = (c == 0) ? g0a : (c == 1) ? g0b : (c == 2) ? g0c : g0d;
    uint4 g1 = (c == 0) ? g1a : (c == 1) ? g1b : (c == 2) ? g1c : g1d;
    float4 pa = ps4[c * 128 + lane * 2];
    float4 pb = ps4[c * 128 + lane * 2 + 1];
    acc0 += bflo(g0.x) * pa.x + bfhi(g0.x) * pa.y;
    acc0 += bflo(g0.y) * pa.z + bfhi(g0.y) * pa.w;
    acc0 += bflo(g0.z) * pb.x + bfhi(g0.z) * pb.y;
    acc0 += bflo(g0.w) * pb.z + bfhi(g0.w) * pb.w;
    acc1 += bflo(g1.x) * pa.x + bfhi(g1.x) * pa.y;
    acc1 += bflo(g1.y) * pa.z + bfhi(g1.y) * pa.w;
    acc1 += bflo(g1.z) * pb.x + bfhi(g1.z) * pb.y;
    acc1 += bflo(g1.w) * pb.z + bfhi(g1.w) * pb.w;
  }
  acc0 = wred(acc0);
  acc1 = wred(acc1);
  if (lane == 0) {
    Qp_out[row0] = acc0 + qcorr[row0] * pshare[row0];
    Qp_out[row0 + 1] = acc1 + qcorr[row0 + 1] * pshare[row0 + 1];
  }
}

// ---------------- final: alpha + out = x + alpha p -----------------------
__global__ __launch_bounds__(256) void k_cgfin(const float* __restrict__ r_last,
    const float* __restrict__ p_last, const float* __restrict__ Qp,
    const float* __restrict__ xcg, float* __restrict__ out) {
  const int tid = threadIdx.x;
  const int lane = tid & 63;
  const float4* r4 = (const float4*)r_last;
  const float4* p4 = (const float4*)p_last;
  const float4* q4 = (const float4*)Qp;
  float rr = 0.f, pap = 0.f;
#pragma unroll
  for (int c = 0; c < 4; ++c) {
#pragma unroll
    for (int hh = 0; hh < 2; ++hh) {
      float4 rv = r4[c * 128 + lane * 2 + hh];
      float4 pv = p4[c * 128 + lane * 2 + hh];
      float4 qv = q4[c * 128 + lane * 2 + hh];
      rr += rv.x * rv.x + rv.y * rv.y + rv.z * rv.z + rv.w * rv.w;
      pap += pv.x * qv.x + pv.y * qv.y + pv.z * qv.z + pv.w * qv.w;
    }
  }
  rr = wred(rr);
  pap = wred(pap);
  float alpha = rr / pap;
  const float4* x4 = (const float4*)xcg;
  float4* o4 = (float4*)out;
#pragma unroll
  for (int hh = 0; hh < 2; ++hh) {
    int i4 = tid * 2 + hh;
    float4 xv = x4[i4];
    float4 pv = p4[i4];
    xv.x += alpha * pv.x; xv.y += alpha * pv.y;
    xv.z += alpha * pv.z; xv.w += alpha * pv.w;
    o4[i4] = xv;
  }
}

// ---------------- launch ----------------

extern "C" void kernel_launch(void* const* d_in, const int* in_sizes, int n_in,
                              void* d_out, int out_size, void* d_ws, size_t ws_size,
                              hipStream_t stream) {
  const float* x      = (const float*)d_in[0];
  const int*   ei     = (const int*)d_in[1];
  const float* A      = (const float*)d_in[2];
  const float* b      = (const float*)d_in[3];
  const int*   fids   = (const int*)d_in[4];
  const float* xprior = (const float*)d_in[5];
  const float* lamb   = (const float*)d_in[6];
  const float* W10    = (const float*)d_in[7];
  const float* W11    = (const float*)d_in[8];
  const float* b1     = (const float*)d_in[9];
  const float* W20    = (const float*)d_in[10];
  const float* W21    = (const float*)d_in[11];
  const float* b2     = (const float*)d_in[12];
  float* out = (float*)d_out;

  char* base = (char*)d_ws;
  size_t o = 0;
  auto alloc = [&](size_t bytes) { size_t r = o; o = (o + bytes + 255) & ~size_t(255); return r; };

  // zero-init region (deg, cursor, xcg, t, s)
  size_t off_deg    = alloc(N_NODES * 4);
  size_t off_cursor = alloc(N_NODES * 4);
  size_t off_xcg    = alloc(NQ * 4);
  size_t off_t      = alloc(N_NODES * 4);
  size_t off_s      = alloc(N_NODES * 4);
  size_t zero_end   = o;
  size_t off_rowst  = alloc((N_NODES + 1) * 4);
  size_t off_dinv   = alloc(N_NODES * 4);
  size_t off_h2     = alloc(N_NODES * 4);
  size_t off_q      = alloc(NQ * 4);
  size_t off_r0     = alloc(NQ * 4);
  size_t off_r1     = alloc(NQ * 4);
  size_t off_p0     = alloc(NQ * 4);
  size_t off_p1     = alloc(NQ * 4);
  size_t off_Qp0    = alloc(NQ * 4);
  size_t off_Qp1    = alloc(NQ * 4);
  size_t off_qcorr  = alloc(NQ * 4);
  size_t off_btAp   = alloc(32 * NQ * 4);
  size_t off_Wtb    = alloc(256 * 128 * 4);
  // union region: GNN {cols, wvals, xmsgb} -> Gb (CG).  Atu SEPARATE.
  size_t sz_cols  = (size_t)N_EDGES * 4 + 256;
  size_t sz_wvals = (size_t)N_EDGES * 4 + 256;
  size_t sz_xmsg  = (size_t)MM_ROWS * 256 * 2;
  size_t union_gnn = sz_cols + sz_wvals + sz_xmsg;
  size_t sz_gb     = (size_t)NQ * NQ * 2;
  size_t off_union = alloc(union_gnn > sz_gb ? union_gnn : sz_gb);
  size_t off_atu   = alloc((size_t)M_ROWS * NQ * 2);          // 16 MB, dedicated
  size_t off_Gp    = alloc((size_t)4 * NTILE * 16384 * 4);    // 35.7 MB
  if (o > ws_size) return;

  int*   deg      = (int*)(base + off_deg);
  int*   cursor   = (int*)(base + off_cursor);
  float* xcg      = (float*)(base + off_xcg);
  float* t        = (float*)(base + off_t);
  float* s        = (float*)(base + off_s);
  int*   rowstart = (int*)(base + off_rowst);
  float* dinv     = (float*)(base + off_dinv);
  float* h2       = (float*)(base + off_h2);
  float* q        = (float*)(base + off_q);
  float* rb[2]    = {(float*)(base + off_r0), (float*)(base + off_r1)};
  float* pg[2]    = {(float*)(base + off_p0), (float*)(base + off_p1)};
  float* Qpb[2]   = {(float*)(base + off_Qp0), (float*)(base + off_Qp1)};
  float* qcorr    = (float*)(base + off_qcorr);
  float* btA_parts = (float*)(base + off_btAp);
  unsigned* Wtb   = (unsigned*)(base + off_Wtb);
  int*   cols     = (int*)(base + off_union);
  float* wvals    = (float*)(base + off_union + sz_cols);
  unsigned* xmsgb = (unsigned*)(base + off_union + sz_cols + sz_wvals);
  unsigned* Gb    = (unsigned*)(base + off_union);  // overwrites cols/xmsgb AFTER h2/mm
  unsigned* Atu   = (unsigned*)(base + off_atu);
  float* Gp       = (float*)(base + off_Gp);

  hipMemsetAsync(d_ws, 0, zero_end, stream);

  // fused front-end: x/W bf16 pack + edge degree count
  k_pack<<<CONVX_BLKS + 128 + DEG_BLKS, 256, 0, stream>>>(x, W10, W11, xmsgb, Wtb, ei, deg);
  k_scan<<<1, 1024, 0, stream>>>(deg, rowstart, dinv);
  k_scatter<<<DEG_BLKS, 256, 0, stream>>>(ei, rowstart, cursor, dinv, cols, wvals);

  // msg gather (xu still L2-hot from k_pack; no big streams in between)
  k_msg1<<<N_NODES / 4, 256, 0, stream>>>(rowstart, cols, wvals, xmsgb);
  k_mm<<<MM_ROWS / 64, 256, 0, stream>>>(xmsgb, Wtb, b1, W20, W21, t, s);

  // A^T prep (LDS transpose, coalesced) -- after mm so xu stays hot for it
  k_prep2<<<1024, 256, 0, stream>>>(A, b, Atu, btA_parts);

  k_h2<<<(N_NODES + 255) / 256, 256, 0, stream>>>(t, s, rowstart, cols, wvals, lamb, b2, h2);

  // Gram (544 blocks) + qrhs tail (8 blocks)
  k_gram<<<552, 512, 0, stream>>>(Atu, Gp, h2, fids, xprior, btA_parts, q, rb[0]);
  k_gconv<<<NTILE, 256, 0, stream>>>(Gp, q, Gb, qcorr);  // Gb overwrites union (dead)

  // CG: 1 kernel/iter
  k_cgG<<<256, 256, 0, stream>>>(0, Gb, qcorr, rb[0], rb[0], pg[0], pg[0],
                                 Qpb[1], Qpb[0], xcg);
  for (int k = 1; k < NIT; ++k) {
    k_cgG<<<256, 256, 0, stream>>>(k, Gb, qcorr, rb[(k - 1) & 1], rb[k & 1],
                                   pg[(k - 1) & 1], pg[k & 1],
                                   Qpb[(k - 1) & 1], Qpb[k & 1], xcg);
  }
  k_cgfin<<<1, 256, 0, stream>>>(rb[(NIT - 1) & 1], pg[(NIT - 1) & 1],
                                 Qpb[(NIT - 1) & 1], xcg, out);
}

// Round 15
// 336.670 us; speedup vs baseline: 1.5908x; 1.0988x over previous
//
#include <hip/hip_runtime.h>

#define N_NODES 20000
#define N_EDGES 320000
#define F_DIM   128
#define H_DIM   256
#define M_ROWS  4096
#define NQ      2048
#define NIT     18
#define MM_ROWS 20032   // 313 * 64, padded row count for bf16 [x|msg]

typedef __attribute__((ext_vector_type(8))) short short8;   // 8 bf16 (4 VGPRs)
typedef __attribute__((ext_vector_type(4))) float f32x4;    // MFMA C/D

// ---------------- helpers ----------------

__device__ __forceinline__ float wred(float v) {
#pragma unroll
  for (int m = 32; m > 0; m >>= 1) v += __shfl_xor(v, m, 64);
  return v;
}

__device__ __forceinline__ float bred256(float v, float* lds) {
  v = wred(v);
  int w = threadIdx.x >> 6;
  if ((threadIdx.x & 63) == 0) lds[w] = v;
  __syncthreads();
  float tot = lds[0] + lds[1] + lds[2] + lds[3];
  __syncthreads();
  return tot;
}

__device__ __forceinline__ unsigned f2bf(float f) {
  unsigned u = __float_as_uint(f);
  unsigned r = u + 0x7fffu + ((u >> 16) & 1u);
  return r >> 16;
}
__device__ __forceinline__ float bflo(unsigned u) { return __uint_as_float(u << 16); }
__device__ __forceinline__ float bfhi(unsigned u) { return __uint_as_float(u & 0xffff0000u); }

// ---------------- CSR build ----------------
// r14 lesson: the old k_scan was 40.6us at 5 GB/s -- single block doing
// stride-80B uncoalesced loops. Stage deg in LDS (80 KB) with coalesced
// grid-stride I/O; chunk sums + 1024-wide scan in LDS; coalesced flush.

__global__ __launch_bounds__(1024) void k_scan(const int* __restrict__ deg,
    int* __restrict__ rowstart, float* __restrict__ dinv) {
  __shared__ int ldeg[N_NODES];   // 80000 B
  __shared__ int part[1024];
  const int t = threadIdx.x;
  // coalesced load deg -> LDS, and dinv out (coalesced)
  for (int i = t; i < N_NODES; i += 1024) {
    int d = deg[i];
    ldeg[i] = d;
    dinv[i] = d > 0 ? rsqrtf((float)d) : 0.f;
  }
  __syncthreads();
  const int chunk = (N_NODES + 1023) / 1024;  // 20
  int lo = t * chunk;
  int hi = lo + chunk; if (hi > N_NODES) hi = N_NODES;
  int s = 0;
  for (int i = lo; i < hi; ++i) s += ldeg[i];
  part[t] = s;
  __syncthreads();
  for (int off = 1; off < 1024; off <<= 1) {
    int v = part[t];
    int add = (t >= off) ? part[t - off] : 0;
    __syncthreads();
    part[t] = v + add;
    __syncthreads();
  }
  int base = (t > 0) ? part[t - 1] : 0;
  // exclusive prefix written back into ldeg in place (own chunk only)
  for (int i = lo; i < hi; ++i) {
    int d = ldeg[i];
    ldeg[i] = base;
    base += d;
  }
  __syncthreads();
  // coalesced flush
  for (int i = t; i < N_NODES; i += 1024) rowstart[i] = ldeg[i];
  if (t == 0) rowstart[N_NODES] = part[1023];
}

__global__ __launch_bounds__(256) void k_scatter(const int* __restrict__ ei,
    const int* __restrict__ rowstart, int* __restrict__ cursor,
    const float* __restrict__ dinv, int* __restrict__ cols, float* __restrict__ wvals) {
  int e = blockIdx.x * 256 + threadIdx.x;
  if (e >= N_EDGES) return;
  int r = ei[e];
  int c = ei[N_EDGES + e];
  int pos = rowstart[r] + atomicAdd(&cursor[r], 1);
  cols[pos] = c;
  wvals[pos] = -dinv[r] * dinv[c];
}

// ------- fused front-end: x pack + W pack + degree count ---------------
#define CONVX_BLKS (MM_ROWS * 16 / 256)     // 1252
#define DEG_BLKS   ((N_EDGES + 255) / 256)  // 1250

__global__ __launch_bounds__(256) void k_pack(const float* __restrict__ x,
    const float* __restrict__ W10, const float* __restrict__ W11,
    unsigned* __restrict__ xu, unsigned* __restrict__ Wtb,
    const int* __restrict__ ei, int* __restrict__ deg) {
  int bx = blockIdx.x;
  if (bx < CONVX_BLKS) {
    int gid = bx * 256 + threadIdx.x;
    int row = gid >> 4;
    int q8 = gid & 15;
    uint4* xu4 = (uint4*)xu;
    if (row < N_NODES) {
      const float4* x4 = (const float4*)x;
      float4 a = x4[(size_t)row * 32 + q8 * 2];
      float4 b2 = x4[(size_t)row * 32 + q8 * 2 + 1];
      uint4 u;
      u.x = f2bf(a.x) | (f2bf(a.y) << 16);
      u.y = f2bf(a.z) | (f2bf(a.w) << 16);
      u.z = f2bf(b2.x) | (f2bf(b2.y) << 16);
      u.w = f2bf(b2.z) | (f2bf(b2.w) << 16);
      xu4[(size_t)row * 32 + q8] = u;
    } else {
      uint4 z = make_uint4(0, 0, 0, 0);
      xu4[(size_t)row * 32 + q8] = z;
      xu4[(size_t)row * 32 + 16 + q8] = z;
    }
  } else if (bx < CONVX_BLKS + 128) {
    int gid = (bx - CONVX_BLKS) * 256 + threadIdx.x;  // 0..32767
    int n = gid >> 7;
    int u = gid & 127;
    int k0 = u * 2;
    float v0 = (k0 < 128) ? W10[(size_t)k0 * H_DIM + n]
                          : W11[(size_t)(k0 - 128) * H_DIM + n];
    float v1 = (k0 + 1 < 128) ? W10[(size_t)(k0 + 1) * H_DIM + n]
                              : W11[(size_t)(k0 - 127) * H_DIM + n];
    Wtb[(size_t)n * 128 + u] = f2bf(v0) | (f2bf(v1) << 16);
  } else {
    int e = (bx - CONVX_BLKS - 128) * 256 + threadIdx.x;
    if (e < N_EDGES) atomicAdd(&deg[ei[e]], 1);
  }
}

// ---------------- A^T bf16 prep via LDS transpose (coalesced writes) ----
#define PT_ST 130

__global__ __launch_bounds__(256) void k_prep2(const float* __restrict__ A,
    const float* __restrict__ b, unsigned* __restrict__ Atu,
    float* __restrict__ btA_parts) {
  __shared__ unsigned short T[64 * PT_ST];   // 16640 B
  __shared__ float part[64 * 4];
  const int t = threadIdx.x;
  const int jt = blockIdx.x & 31, kt = blockIdx.x >> 5;
  const int j0 = jt * 64, k0 = kt * 128;
  const int jl = t & 63, kq = t >> 6;        // read: col j0+jl, row k0+p*4+kq
  float bta = 0.f;
#pragma unroll 8
  for (int p = 0; p < 32; ++p) {
    int row = k0 + p * 4 + kq;
    float v = A[(size_t)row * NQ + j0 + jl];
    bta += b[row] * v;
    T[jl * PT_ST + p * 4 + kq] = (unsigned short)f2bf(v);
  }
  part[jl * 4 + kq] = bta;
  __syncthreads();
  // write: 4 threads per Atu row, 16 uints (64B) each -> coalesced 256B/row
  const int jr = t >> 2, c = t & 3;
  const unsigned short* Tr = T + jr * PT_ST + c * 32;
  uint4 uu0, uu1, uu2, uu3;
  uu0.x = (unsigned)Tr[0]  | ((unsigned)Tr[1]  << 16);
  uu0.y = (unsigned)Tr[2]  | ((unsigned)Tr[3]  << 16);
  uu0.z = (unsigned)Tr[4]  | ((unsigned)Tr[5]  << 16);
  uu0.w = (unsigned)Tr[6]  | ((unsigned)Tr[7]  << 16);
  uu1.x = (unsigned)Tr[8]  | ((unsigned)Tr[9]  << 16);
  uu1.y = (unsigned)Tr[10] | ((unsigned)Tr[11] << 16);
  uu1.z = (unsigned)Tr[12] | ((unsigned)Tr[13] << 16);
  uu1.w = (unsigned)Tr[14] | ((unsigned)Tr[15] << 16);
  uu2.x = (unsigned)Tr[16] | ((unsigned)Tr[17] << 16);
  uu2.y = (unsigned)Tr[18] | ((unsigned)Tr[19] << 16);
  uu2.z = (unsigned)Tr[20] | ((unsigned)Tr[21] << 16);
  uu2.w = (unsigned)Tr[22] | ((unsigned)Tr[23] << 16);
  uu3.x = (unsigned)Tr[24] | ((unsigned)Tr[25] << 16);
  uu3.y = (unsigned)Tr[26] | ((unsigned)Tr[27] << 16);
  uu3.z = (unsigned)Tr[28] | ((unsigned)Tr[29] << 16);
  uu3.w = (unsigned)Tr[30] | ((unsigned)Tr[31] << 16);
  uint4* dst = (uint4*)(Atu + (size_t)(j0 + jr) * 2048 + kt * 64 + c * 16);
  dst[0] = uu0; dst[1] = uu1; dst[2] = uu2; dst[3] = uu3;
  if (t < 64) {
    float s4 = (part[t * 4] + part[t * 4 + 1]) + (part[t * 4 + 2] + part[t * 4 + 3]);
    btA_parts[(size_t)kt * NQ + j0 + t] = s4;
  }
}

// ---------------- msg gather, 4-deep unrolled (MLP fix, r10) ------------
__global__ __launch_bounds__(256) void k_msg1(const int* __restrict__ rowstart,
    const int* __restrict__ cols, const float* __restrict__ wvals,
    unsigned* __restrict__ xu) {
  int wid = (blockIdx.x * 256 + threadIdx.x) >> 6;
  int lane = threadIdx.x & 63;
  if (wid >= N_NODES) return;
  int s0 = rowstart[wid], s1 = rowstart[wid + 1];
  float2 a0 = make_float2(0.f, 0.f), a1 = make_float2(0.f, 0.f);
  float2 a2 = make_float2(0.f, 0.f), a3 = make_float2(0.f, 0.f);
  int e = s0;
  for (; e + 4 <= s1; e += 4) {
    int c0 = cols[e], c1 = cols[e + 1], c2 = cols[e + 2], c3 = cols[e + 3];
    float w0 = wvals[e], w1 = wvals[e + 1], w2 = wvals[e + 2], w3 = wvals[e + 3];
    unsigned u0 = xu[(size_t)c0 * 128 + lane];
    unsigned u1 = xu[(size_t)c1 * 128 + lane];
    unsigned u2 = xu[(size_t)c2 * 128 + lane];
    unsigned u3 = xu[(size_t)c3 * 128 + lane];
    a0.x += w0 * bflo(u0); a0.y += w0 * bfhi(u0);
    a1.x += w1 * bflo(u1); a1.y += w1 * bfhi(u1);
    a2.x += w2 * bflo(u2); a2.y += w2 * bfhi(u2);
    a3.x += w3 * bflo(u3); a3.y += w3 * bfhi(u3);
  }
  for (; e < s1; ++e) {
    int c = cols[e];
    float w = wvals[e];
    unsigned u = xu[(size_t)c * 128 + lane];
    a0.x += w * bflo(u); a0.y += w * bfhi(u);
  }
  float ax = (a0.x + a1.x) + (a2.x + a3.x);
  float ay = (a0.y + a1.y) + (a2.y + a3.y);
  xu[(size_t)wid * 128 + 64 + lane] = f2bf(ax) | (f2bf(ay) << 16);
}

// ---------------- GNN layer-1 GEMM via MFMA (LDS-free, barrier-free) ----

__device__ __forceinline__ void mm_ldfrag(short8* Af, short8* Bf,
    const unsigned* __restrict__ xurow, const unsigned* __restrict__ wrow, int kc) {
#pragma unroll
  for (int a = 0; a < 4; ++a)
    Af[a] = *(const short8*)(xurow + (size_t)a * 16 * 128 + kc * 16);
#pragma unroll
  for (int n = 0; n < 4; ++n)
    Bf[n] = *(const short8*)(wrow + (size_t)n * 16 * 128 + kc * 16);
}

__global__ __launch_bounds__(256) void k_mm(const unsigned* __restrict__ xu,
    const unsigned* __restrict__ Wtb, const float* __restrict__ b1,
    const float* __restrict__ W20, const float* __restrict__ W21,
    float* __restrict__ t, float* __restrict__ s) {
  const int row0 = blockIdx.x * 64;
  const int tid = threadIdx.x;
  const int w = tid >> 6, lane = tid & 63;
  const int colb = w * 64;
  const int frow = lane & 15, fqo = (lane >> 4) * 4;
  const int c16 = lane & 15, q4 = lane >> 4;

  f32x4 acc[4][4];
#pragma unroll
  for (int a = 0; a < 4; ++a)
#pragma unroll
    for (int b = 0; b < 4; ++b) {
      acc[a][b][0] = 0.f; acc[a][b][1] = 0.f;
      acc[a][b][2] = 0.f; acc[a][b][3] = 0.f;
    }

  const unsigned* xurow = xu + (size_t)(row0 + frow) * 128 + fqo;
  const unsigned* wrow  = Wtb + (size_t)(colb + frow) * 128 + fqo;

  short8 A0[4], B0[4], A1[4], B1[4];
  mm_ldfrag(A0, B0, xurow, wrow, 0);
#pragma unroll
  for (int kp = 0; kp < 4; ++kp) {
    const int kc = kp * 2;
    mm_ldfrag(A1, B1, xurow, wrow, kc + 1);
#pragma unroll
    for (int a = 0; a < 4; ++a)
#pragma unroll
      for (int n = 0; n < 4; ++n)
        acc[a][n] = __builtin_amdgcn_mfma_f32_16x16x32_bf16(A0[a], B0[n], acc[a][n], 0, 0, 0);
    if (kc + 2 < 8) mm_ldfrag(A0, B0, xurow, wrow, kc + 2);
#pragma unroll
    for (int a = 0; a < 4; ++a)
#pragma unroll
      for (int n = 0; n < 4; ++n)
        acc[a][n] = __builtin_amdgcn_mfma_f32_16x16x32_bf16(A1[a], B1[n], acc[a][n], 0, 0, 0);
  }

  float tp[4][4] = {}, sp[4][4] = {};
#pragma unroll
  for (int b2 = 0; b2 < 4; ++b2) {
    int gc = colb + b2 * 16 + c16;
    float w20 = W20[gc], w21 = W21[gc], bb = b1[gc];
#pragma unroll
    for (int a = 0; a < 4; ++a)
#pragma unroll
      for (int r = 0; r < 4; ++r) {
        float val = acc[a][b2][r] + bb;
        val = val > 0.f ? val : 0.f;
        tp[a][r] += val * w20;
        sp[a][r] += val * w21;
      }
  }
#pragma unroll
  for (int a = 0; a < 4; ++a)
#pragma unroll
    for (int r = 0; r < 4; ++r) {
#pragma unroll
      for (int m = 1; m < 16; m <<= 1) {
        tp[a][r] += __shfl_xor(tp[a][r], m, 64);
        sp[a][r] += __shfl_xor(sp[a][r], m, 64);
      }
    }
  if (c16 == 0) {
#pragma unroll
    for (int a = 0; a < 4; ++a)
#pragma unroll
      for (int r = 0; r < 4; ++r) {
        int gr = row0 + a * 16 + q4 * 4 + r;
        if (gr < N_NODES) {
          atomicAdd(&t[gr], tp[a][r]);
          atomicAdd(&s[gr], sp[a][r]);
        }
      }
  }
}

// ---------------- GNN layer 2 scalar gather (4-deep unrolled) -----------

__global__ __launch_bounds__(256) void k_h2(const float* __restrict__ t,
    const float* __restrict__ s, const int* __restrict__ rowstart,
    const int* __restrict__ cols, const float* __restrict__ wvals,
    const float* __restrict__ lamb, const float* __restrict__ b2, float* __restrict__ h2) {
  int i = blockIdx.x * 256 + threadIdx.x;
  if (i >= N_NODES) return;
  int s0 = rowstart[i], s1 = rowstart[i + 1];
  float m0 = 0.f, m1 = 0.f, m2 = 0.f, m3 = 0.f;
  int e = s0;
  for (; e + 4 <= s1; e += 4) {
    int c0 = cols[e], c1 = cols[e + 1], c2 = cols[e + 2], c3 = cols[e + 3];
    float w0 = wvals[e], w1 = wvals[e + 1], w2 = wvals[e + 2], w3 = wvals[e + 3];
    m0 += w0 * s[c0];
    m1 += w1 * s[c1];
    m2 += w2 * s[c2];
    m3 += w3 * s[c3];
  }
  for (; e < s1; ++e) m0 += wvals[e] * s[cols[e]];
  float m = (m0 + m1) + (m2 + m3);
  float val = t[i] + m + b2[0];
  val = val > 0.f ? val : 0.f;
  h2[i] = lamb[0] * val;
}

// ---------------- G partials = A^T A, SYMMETRIC upper triangle ----------
// 544 compute blocks (136 tiles x 4 K-quarters, K_STEP=64) + 8 qrhs tail.
// r13 lesson: NO intra-grid cross-XCD combine. Kernel boundary = cheap
// coherence.
#define GR_ST2 36
#define NTILE 136

__global__ __launch_bounds__(512) void k_gram(const unsigned* __restrict__ Atu,
    float* __restrict__ Gp,
    const float* __restrict__ h2, const int* __restrict__ feat_ids,
    const float* __restrict__ x_prior, const float* __restrict__ btA_parts,
    float* __restrict__ q, float* __restrict__ r0) {
  if (blockIdx.x >= 544) {
    if (threadIdx.x < 256) {
      int j = (blockIdx.x - 544) * 256 + threadIdx.x;
      int f = feat_ids[j];
      float hf = h2[f] + 1e-5f;
      q[j] = hf;
      float bta = 0.f;
#pragma unroll
      for (int c = 0; c < 32; ++c) bta += btA_parts[(size_t)c * NQ + j];
      r0[j] = x_prior[j] * hf + bta;  // rhs = -p
    }
    return;
  }
  __shared__ unsigned shA[128 * GR_ST2];  // 18432 B
  __shared__ unsigned shB[128 * GR_ST2];  // 18432 B
  const int bid = blockIdx.x;            // 0..543
  const int wid = (bid & 7) * 68 + (bid >> 3);
  const int tile = wid >> 2;             // 0..135, tile-major
  const int kq = wid & 3;                // K-quarter: uints [kq*512, kq*512+512)
  int uu = tile, bi = 0;
  while (uu >= 16 - bi) { uu -= 16 - bi; ++bi; }
  const int bj = bi + uu;
  const int i0 = bi * 128, j0 = bj * 128;
  const int tid = threadIdx.x;           // 0..511
  const int w = tid >> 6, lane = tid & 63;
  const int wr = (w >> 2) * 64, wc = (w & 3) * 32;   // 2x4 wave tiles, 64x32 each
  const int srow = tid >> 2, sua = (tid & 3) * 8;    // staging: rows 0..127, 8 uints each
  const int frow = lane & 15, fqo = (lane >> 4) * 4;

  f32x4 acc[4][2];
#pragma unroll
  for (int a = 0; a < 4; ++a)
#pragma unroll
    for (int b = 0; b < 2; ++b) {
      acc[a][b][0] = 0.f; acc[a][b][1] = 0.f;
      acc[a][b][2] = 0.f; acc[a][b][3] = 0.f;
    }

  const unsigned* pa = Atu + (size_t)(i0 + srow) * 2048 + kq * 512 + sua;
  const unsigned* pb = Atu + (size_t)(j0 + srow) * 2048 + kq * 512 + sua;

  uint4 pra0 = *(const uint4*)(pa);
  uint4 pra1 = *(const uint4*)(pa + 4);
  uint4 prb0 = *(const uint4*)(pb);
  uint4 prb1 = *(const uint4*)(pb + 4);

  unsigned* as = shA + srow * GR_ST2 + sua;
  unsigned* bs = shB + srow * GR_ST2 + sua;

  for (int sp = 0; sp < 16; ++sp) {
    *(uint4*)as = pra0; *(uint4*)(as + 4) = pra1;
    *(uint4*)bs = prb0; *(uint4*)(bs + 4) = prb1;
    if (sp + 1 < 16) {
      const int ku = (sp + 1) * 32;
      pra0 = *(const uint4*)(pa + ku);
      pra1 = *(const uint4*)(pa + ku + 4);
      prb0 = *(const uint4*)(pb + ku);
      prb1 = *(const uint4*)(pb + ku + 4);
    }
    __syncthreads();
#pragma unroll
    for (int kk = 0; kk < 2; ++kk) {
      short8 af[4], bf[2];
#pragma unroll
      for (int a = 0; a < 4; ++a)
        af[a] = *(const short8*)(shA + (wr + a * 16 + frow) * GR_ST2 + kk * 16 + fqo);
#pragma unroll
      for (int b2 = 0; b2 < 2; ++b2)
        bf[b2] = *(const short8*)(shB + (wc + b2 * 16 + frow) * GR_ST2 + kk * 16 + fqo);
#pragma unroll
      for (int a = 0; a < 4; ++a)
#pragma unroll
        for (int b2 = 0; b2 < 2; ++b2)
          acc[a][b2] = __builtin_amdgcn_mfma_f32_16x16x32_bf16(af[a], bf[b2], acc[a][b2], 0, 0, 0);
    }
    __syncthreads();
  }

  const int q4 = lane >> 4, c16 = lane & 15;
  float* Gz = Gp + ((size_t)kq * NTILE + tile) * 16384;
#pragma unroll
  for (int a = 0; a < 4; ++a)
#pragma unroll
    for (int b2 = 0; b2 < 2; ++b2)
#pragma unroll
      for (int r = 0; r < 4; ++r) {
        int lr = wr + a * 16 + q4 * 4 + r;
        int lc = wc + b2 * 16 + c16;
        Gz[lr * 128 + lc] = acc[a][b2][r];
      }
}

// ---------------- combine K-quarters + diag(q) -> bf16 Gb (+mirror) -----
#define GT_ST 131

__global__ __launch_bounds__(256) void k_gconv(const float* __restrict__ Gp,
    const float* __restrict__ q, unsigned* __restrict__ Gb, float* __restrict__ qcorr) {
  __shared__ unsigned short T[128 * GT_ST];  // 33536 B
  int uu = blockIdx.x, bi = 0;
  while (uu >= 16 - bi) { uu -= 16 - bi; ++bi; }
  const int bj = bi + uu;
  const int tid = threadIdx.x;
  const int r = tid >> 1, ch = (tid & 1) * 64;   // tile row, col half
  const size_t tile = (size_t)blockIdx.x * 16384;
  const float4* P0 = (const float4*)(Gp + tile + r * 128 + ch);
  const float4* P1 = (const float4*)(Gp + (size_t)1 * NTILE * 16384 + tile + r * 128 + ch);
  const float4* P2 = (const float4*)(Gp + (size_t)2 * NTILE * 16384 + tile + r * 128 + ch);
  const float4* P3 = (const float4*)(Gp + (size_t)3 * NTILE * 16384 + tile + r * 128 + ch);
  const int gr = bi * 128 + r;
  const bool hasdiag = (bi == bj) && (r >= ch) && (r < ch + 64);
  unsigned uo[32];
#pragma unroll
  for (int j = 0; j < 16; ++j) {
    float4 a = P0[j], b = P1[j], c = P2[j], d = P3[j];
    float v0 = a.x + b.x + c.x + d.x;
    float v1 = a.y + b.y + c.y + d.y;
    float v2 = a.z + b.z + c.z + d.z;
    float v3 = a.w + b.w + c.w + d.w;
    const int c0 = ch + j * 4;
    if (hasdiag && (r - c0 >= 0) && (r - c0 < 4)) {
      float qv = q[gr];
      int dsel = r - c0;
      if (dsel == 0) v0 += qv;
      else if (dsel == 1) v1 += qv;
      else if (dsel == 2) v2 += qv;
      else v3 += qv;
      float vd = (dsel == 0) ? v0 : (dsel == 1) ? v1 : (dsel == 2) ? v2 : v3;
      qcorr[gr] = vd - bflo(f2bf(vd));
    }
    unsigned u0 = f2bf(v0) | (f2bf(v1) << 16);
    unsigned u1 = f2bf(v2) | (f2bf(v3) << 16);
    uo[2 * j] = u0;
    uo[2 * j + 1] = u1;
    T[r * GT_ST + c0]     = (unsigned short)(u0 & 0xffffu);
    T[r * GT_ST + c0 + 1] = (unsigned short)(u0 >> 16);
    T[r * GT_ST + c0 + 2] = (unsigned short)(u1 & 0xffffu);
    T[r * GT_ST + c0 + 3] = (unsigned short)(u1 >> 16);
  }
  uint4* dst = (uint4*)(Gb + (size_t)gr * 1024 + bj * 64 + (ch >> 1));
#pragma unroll
  for (int j = 0; j < 8; ++j) dst[j] = ((const uint4*)uo)[j];
  __syncthreads();
  if (bi != bj) {
    const int wv = tid >> 6, lane = tid & 63;
    for (int kk = 0; kk < 32; ++kk) {
      int rr = kk * 4 + wv;
      unsigned lo = T[(2 * lane) * GT_ST + rr];
      unsigned hi = T[(2 * lane + 1) * GT_ST + rr];
      Gb[(size_t)(bj * 128 + rr) * 1024 + bi * 64 + lane] = lo | (hi << 16);
    }
  }
}

// ---------------- CG: ONE kernel/iter.  Qp = Gb p + qcorr*p -------------
// 256 blocks; each wave owns TWO G-rows (r12-proven form).
__global__ __launch_bounds__(256) void k_cgG(int k, const unsigned* __restrict__ Gb,
    const float* __restrict__ qcorr,
    const float* __restrict__ r_old, float* __restrict__ r_new,
    const float* __restrict__ p_old, float* __restrict__ p_new,
    const float* __restrict__ Qp_in, float* __restrict__ Qp_out,
    float* __restrict__ xcg) {
  __shared__ float pshare[NQ];
  __shared__ float lds[4];
  const int tid = threadIdx.x, bid = blockIdx.x;
  const float4* r4 = (const float4*)r_old;
  float4 ra = r4[tid * 2], rb2 = r4[tid * 2 + 1];
  float pv[8];
  if (k == 0) {
    pv[0] = ra.x; pv[1] = ra.y; pv[2] = ra.z; pv[3] = ra.w;
    pv[4] = rb2.x; pv[5] = rb2.y; pv[6] = rb2.z; pv[7] = rb2.w;
    if (bid == 0) {
      ((float4*)p_new)[tid * 2] = ra;
      ((float4*)p_new)[tid * 2 + 1] = rb2;
    }
  } else {
    const float4* p4 = (const float4*)p_old;
    const float4* qp4 = (const float4*)Qp_in;
    float4 pa = p4[tid * 2], pb = p4[tid * 2 + 1];
    float4 qa = qp4[tid * 2], qb = qp4[tid * 2 + 1];
    float rr = ra.x * ra.x + ra.y * ra.y + ra.z * ra.z + ra.w * ra.w +
               rb2.x * rb2.x + rb2.y * rb2.y + rb2.z * rb2.z + rb2.w * rb2.w;
    float pap = pa.x * qa.x + pa.y * qa.y + pa.z * qa.z + pa.w * qa.w +
                pb.x * qb.x + pb.y * qb.y + pb.z * qb.z + pb.w * qb.w;
    rr = bred256(rr, lds);
    pap = bred256(pap, lds);
    float alpha = rr / pap;
    if (bid == 0) {
      float4* x4 = (float4*)xcg;
      float4 xa = x4[tid * 2], xb = x4[tid * 2 + 1];
      xa.x += alpha * pa.x; xa.y += alpha * pa.y;
      xa.z += alpha * pa.z; xa.w += alpha * pa.w;
      xb.x += alpha * pb.x; xb.y += alpha * pb.y;
      xb.z += alpha * pb.z; xb.w += alpha * pb.w;
      x4[tid * 2] = xa; x4[tid * 2 + 1] = xb;
    }
    ra.x -= alpha * qa.x; ra.y -= alpha * qa.y;
    ra.z -= alpha * qa.z; ra.w -= alpha * qa.w;
    rb2.x -= alpha * qb.x; rb2.y -= alpha * qb.y;
    rb2.z -= alpha * qb.z; rb2.w -= alpha * qb.w;
    float rrn = ra.x * ra.x + ra.y * ra.y + ra.z * ra.z + ra.w * ra.w +
                rb2.x * rb2.x + rb2.y * rb2.y + rb2.z * rb2.z + rb2.w * rb2.w;
    rrn = bred256(rrn, lds);
    float beta = rrn / rr;
    pv[0] = ra.x + beta * pa.x; pv[1] = ra.y + beta * pa.y;
    pv[2] = ra.z + beta * pa.z; pv[3] = ra.w + beta * pa.w;
    pv[4] = rb2.x + beta * pb.x; pv[5] = rb2.y + beta * pb.y;
    pv[6] = rb2.z + beta * pb.z; pv[7] = rb2.w + beta * pb.w;
    if (bid == 0) {
      ((float4*)r_new)[tid * 2] = ra;
      ((float4*)r_new)[tid * 2 + 1] = rb2;
      ((float4*)p_new)[tid * 2] = make_float4(pv[0], pv[1], pv[2], pv[3]);
      ((float4*)p_new)[tid * 2 + 1] = make_float4(pv[4], pv[5], pv[6], pv[7]);
    }
  }
  ((float4*)pshare)[tid * 2] = make_float4(pv[0], pv[1], pv[2], pv[3]);
  ((float4*)pshare)[tid * 2 + 1] = make_float4(pv[4], pv[5], pv[6], pv[7]);
  __syncthreads();
  // matvec: two bf16 G-rows per wave (+ fp32 diag correction)
  const int w = tid >> 6, lane = tid & 63;
  const int row0 = bid * 8 + w * 2;
  const uint4* Gr0 = (const uint4*)(Gb + (size_t)row0 * 1024);
  const uint4* Gr1 = (const uint4*)(Gb + (size_t)(row0 + 1) * 1024);
  const float4* ps4 = (const float4*)pshare;
  float acc0 = 0.f, acc1 = 0.f;
#pragma unroll
  for (int c = 0; c < 4; ++c) {
    uint4 g0 = Gr0[c * 64 + lane];
    uint4 g1 = Gr1[c * 64 + lane];
    float4 pa = ps4[c * 128 + lane * 2];
    float4 pb = ps4[c * 128 + lane * 2 + 1];
    acc0 += bflo(g0.x) * pa.x + bfhi(g0.x) * pa.y;
    acc0 += bflo(g0.y) * pa.z + bfhi(g0.y) * pa.w;
    acc0 += bflo(g0.z) * pb.x + bfhi(g0.z) * pb.y;
    acc0 += bflo(g0.w) * pb.z + bfhi(g0.w) * pb.w;
    acc1 += bflo(g1.x) * pa.x + bfhi(g1.x) * pa.y;
    acc1 += bflo(g1.y) * pa.z + bfhi(g1.y) * pa.w;
    acc1 += bflo(g1.z) * pb.x + bfhi(g1.z) * pb.y;
    acc1 += bflo(g1.w) * pb.z + bfhi(g1.w) * pb.w;
  }
  acc0 = wred(acc0);
  acc1 = wred(acc1);
  if (lane == 0) {
    Qp_out[row0] = acc0 + qcorr[row0] * pshare[row0];
    Qp_out[row0 + 1] = acc1 + qcorr[row0 + 1] * pshare[row0 + 1];
  }
}

// ---------------- final: alpha + out = x + alpha p -----------------------
__global__ __launch_bounds__(256) void k_cgfin(const float* __restrict__ r_last,
    const float* __restrict__ p_last, const float* __restrict__ Qp,
    const float* __restrict__ xcg, float* __restrict__ out) {
  const int tid = threadIdx.x;
  const int lane = tid & 63;
  const float4* r4 = (const float4*)r_last;
  const float4* p4 = (const float4*)p_last;
  const float4* q4 = (const float4*)Qp;
  float rr = 0.f, pap = 0.f;
#pragma unroll
  for (int c = 0; c < 4; ++c) {
#pragma unroll
    for (int hh = 0; hh < 2; ++hh) {
      float4 rv = r4[c * 128 + lane * 2 + hh];
      float4 pv = p4[c * 128 + lane * 2 + hh];
      float4 qv = q4[c * 128 + lane * 2 + hh];
      rr += rv.x * rv.x + rv.y * rv.y + rv.z * rv.z + rv.w * rv.w;
      pap += pv.x * qv.x + pv.y * qv.y + pv.z * qv.z + pv.w * qv.w;
    }
  }
  rr = wred(rr);
  pap = wred(pap);
  float alpha = rr / pap;
  const float4* x4 = (const float4*)xcg;
  float4* o4 = (float4*)out;
#pragma unroll
  for (int hh = 0; hh < 2; ++hh) {
    int i4 = tid * 2 + hh;
    float4 xv = x4[i4];
    float4 pv = p4[i4];
    xv.x += alpha * pv.x; xv.y += alpha * pv.y;
    xv.z += alpha * pv.z; xv.w += alpha * pv.w;
    o4[i4] = xv;
  }
}

// ---------------- launch ----------------

extern "C" void kernel_launch(void* const* d_in, const int* in_sizes, int n_in,
                              void* d_out, int out_size, void* d_ws, size_t ws_size,
                              hipStream_t stream) {
  const float* x      = (const float*)d_in[0];
  const int*   ei     = (const int*)d_in[1];
  const float* A      = (const float*)d_in[2];
  const float* b      = (const float*)d_in[3];
  const int*   fids   = (const int*)d_in[4];
  const float* xprior = (const float*)d_in[5];
  const float* lamb   = (const float*)d_in[6];
  const float* W10    = (const float*)d_in[7];
  const float* W11    = (const float*)d_in[8];
  const float* b1     = (const float*)d_in[9];
  const float* W20    = (const float*)d_in[10];
  const float* W21    = (const float*)d_in[11];
  const float* b2     = (const float*)d_in[12];
  float* out = (float*)d_out;

  char* base = (char*)d_ws;
  size_t o = 0;
  auto alloc = [&](size_t bytes) { size_t r = o; o = (o + bytes + 255) & ~size_t(255); return r; };

  // zero-init region (deg, cursor, xcg, t, s)
  size_t off_deg    = alloc(N_NODES * 4);
  size_t off_cursor = alloc(N_NODES * 4);
  size_t off_xcg    = alloc(NQ * 4);
  size_t off_t      = alloc(N_NODES * 4);
  size_t off_s      = alloc(N_NODES * 4);
  size_t zero_end   = o;
  size_t off_rowst  = alloc((N_NODES + 1) * 4);
  size_t off_dinv   = alloc(N_NODES * 4);
  size_t off_h2     = alloc(N_NODES * 4);
  size_t off_q      = alloc(NQ * 4);
  size_t off_r0     = alloc(NQ * 4);
  size_t off_r1     = alloc(NQ * 4);
  size_t off_p0     = alloc(NQ * 4);
  size_t off_p1     = alloc(NQ * 4);
  size_t off_Qp0    = alloc(NQ * 4);
  size_t off_Qp1    = alloc(NQ * 4);
  size_t off_qcorr  = alloc(NQ * 4);
  size_t off_btAp   = alloc(32 * NQ * 4);
  size_t off_Wtb    = alloc(256 * 128 * 4);
  // union region: GNN {cols, wvals, xmsgb} -> Gb (CG).  Atu SEPARATE.
  size_t sz_cols  = (size_t)N_EDGES * 4 + 256;
  size_t sz_wvals = (size_t)N_EDGES * 4 + 256;
  size_t sz_xmsg  = (size_t)MM_ROWS * 256 * 2;
  size_t union_gnn = sz_cols + sz_wvals + sz_xmsg;
  size_t sz_gb     = (size_t)NQ * NQ * 2;
  size_t off_union = alloc(union_gnn > sz_gb ? union_gnn : sz_gb);
  size_t off_atu   = alloc((size_t)M_ROWS * NQ * 2);          // 16 MB, dedicated
  size_t off_Gp    = alloc((size_t)4 * NTILE * 16384 * 4);    // 35.7 MB
  if (o > ws_size) return;

  int*   deg      = (int*)(base + off_deg);
  int*   cursor   = (int*)(base + off_cursor);
  float* xcg      = (float*)(base + off_xcg);
  float* t        = (float*)(base + off_t);
  float* s        = (float*)(base + off_s);
  int*   rowstart = (int*)(base + off_rowst);
  float* dinv     = (float*)(base + off_dinv);
  float* h2       = (float*)(base + off_h2);
  float* q        = (float*)(base + off_q);
  float* rb[2]    = {(float*)(base + off_r0), (float*)(base + off_r1)};
  float* pg[2]    = {(float*)(base + off_p0), (float*)(base + off_p1)};
  float* Qpb[2]   = {(float*)(base + off_Qp0), (float*)(base + off_Qp1)};
  float* qcorr    = (float*)(base + off_qcorr);
  float* btA_parts = (float*)(base + off_btAp);
  unsigned* Wtb   = (unsigned*)(base + off_Wtb);
  int*   cols     = (int*)(base + off_union);
  float* wvals    = (float*)(base + off_union + sz_cols);
  unsigned* xmsgb = (unsigned*)(base + off_union + sz_cols + sz_wvals);
  unsigned* Gb    = (unsigned*)(base + off_union);  // overwrites cols/xmsgb AFTER h2/mm
  unsigned* Atu   = (unsigned*)(base + off_atu);
  float* Gp       = (float*)(base + off_Gp);

  hipMemsetAsync(d_ws, 0, zero_end, stream);

  // fused front-end: x/W bf16 pack + edge degree count
  k_pack<<<CONVX_BLKS + 128 + DEG_BLKS, 256, 0, stream>>>(x, W10, W11, xmsgb, Wtb, ei, deg);
  k_scan<<<1, 1024, 0, stream>>>(deg, rowstart, dinv);
  k_scatter<<<DEG_BLKS, 256, 0, stream>>>(ei, rowstart, cursor, dinv, cols, wvals);

  // msg gather (xu still L2-hot from k_pack; no big streams in between)
  k_msg1<<<N_NODES / 4, 256, 0, stream>>>(rowstart, cols, wvals, xmsgb);
  k_mm<<<MM_ROWS / 64, 256, 0, stream>>>(xmsgb, Wtb, b1, W20, W21, t, s);

  // A^T prep (LDS transpose, coalesced) -- after mm so xu stays hot for it
  k_prep2<<<1024, 256, 0, stream>>>(A, b, Atu, btA_parts);

  k_h2<<<(N_NODES + 255) / 256, 256, 0, stream>>>(t, s, rowstart, cols, wvals, lamb, b2, h2);

  // Gram (544 blocks) + qrhs tail (8 blocks)
  k_gram<<<552, 512, 0, stream>>>(Atu, Gp, h2, fids, xprior, btA_parts, q, rb[0]);
  k_gconv<<<NTILE, 256, 0, stream>>>(Gp, q, Gb, qcorr);  // Gb overwrites union (dead)

  // CG: 1 kernel/iter
  k_cgG<<<256, 256, 0, stream>>>(0, Gb, qcorr, rb[0], rb[0], pg[0], pg[0],
                                 Qpb[1], Qpb[0], xcg);
  for (int k = 1; k < NIT; ++k) {
    k_cgG<<<256, 256, 0, stream>>>(k, Gb, qcorr, rb[(k - 1) & 1], rb[k & 1],
                                   pg[(k - 1) & 1], pg[k & 1],
                                   Qpb[(k - 1) & 1], Qpb[k & 1], xcg);
  }
  k_cgfin<<<1, 256, 0, stream>>>(rb[(NIT - 1) & 1], pg[(NIT - 1) & 1],
                                 Qpb[(NIT - 1) & 1], xcg, out);
}